// Round 3
// baseline (12997.081 us; speedup 1.0000x reference)
//
#include <hip/hip_runtime.h>

typedef float f32x4 __attribute__((ext_vector_type(4)));
typedef short bf16x8 __attribute__((ext_vector_type(8)));

#define SLEN 128
#define TLEN 127
#define VOC 36
#define NPROBS (4096*127*36)
#define MLOSS_OFF NPROBS
#define LOSS_OFF (NPROBS + 4096)

#define ROWS 32          // rows per block
#define NBLK 128

// ws layout (bytes). Packed wave-major weight layouts:
//  W0p[wv][G][kt][lane][8]  wv<16,G<4,kt<12 -> 393216 shorts
//  W1p[wv][G][kt][lane][8]  wv<16,G<4,kt<16 -> 524288 shorts
//  FCp[n][kt][lane][8]      n<3,kt<8        -> 12288 shorts
#define WS_W0 0
#define WS_W1 786432
#define WS_FC 1835008
#define WS_B0 1859584                // float[1024]
#define WS_B1 1863680                // float[1024]
#define WS_BAR 1867776               // unsigned[1]

#define NW0 393216
#define NW1 524288
#define NFC 12288

__device__ __forceinline__ short f2bf(float f){
  unsigned u = __float_as_uint(f);
  u += 0x7fffu + ((u >> 16) & 1u);
  return (short)(u >> 16);
}
__device__ __forceinline__ float fsig(float x){ return 1.0f/(1.0f + __expf(-x)); }
__device__ __forceinline__ float ftanh(float x){ return 1.0f - 2.0f/(1.0f + __expf(2.0f*x)); }

__global__ void prep_kernel(const float* __restrict__ Wih0, const float* __restrict__ Whh0,
                            const float* __restrict__ bih0, const float* __restrict__ bhh0,
                            const float* __restrict__ Wih1, const float* __restrict__ Whh1,
                            const float* __restrict__ bih1, const float* __restrict__ bhh1,
                            const float* __restrict__ fcW,
                            short* __restrict__ w0, short* __restrict__ w1, short* __restrict__ fcw,
                            float* __restrict__ b0, float* __restrict__ b1,
                            unsigned* __restrict__ bar,
                            float* __restrict__ out)
{
  int idx = blockIdx.x*256 + threadIdx.x;
  if (idx == 0) { out[LOSS_OFF] = 0.0f; *bar = 0u; }
  if (idx < NW0) {
    int wv = idx / 24576;
    int r1 = idx - wv*24576;
    int G  = r1 / 6144;
    int r2 = r1 - G*6144;
    int kt = r2 / 512;
    int r3 = r2 - kt*512;
    int ln = r3 >> 3, e = r3 & 7;
    int row = G*256 + wv*16 + (ln & 15);
    int col = kt*32 + (ln>>4)*8 + e;
    float v = (col < 128) ? Wih0[row*128 + col] : Whh0[row*256 + (col-128)];
    w0[idx] = f2bf(v);
  } else if (idx < NW0 + NW1) {
    int i2 = idx - NW0;
    int wv = i2 / 32768;
    int r1 = i2 - wv*32768;
    int G  = r1 / 8192;
    int r2 = r1 - G*8192;
    int kt = r2 / 512;
    int r3 = r2 - kt*512;
    int ln = r3 >> 3, e = r3 & 7;
    int row = G*256 + wv*16 + (ln & 15);
    int col = kt*32 + (ln>>4)*8 + e;
    float v = (col < 256) ? Wih1[row*256 + col] : Whh1[row*256 + (col-256)];
    w1[i2] = f2bf(v);
  } else if (idx < NW0 + NW1 + NFC) {
    int i2 = idx - (NW0 + NW1);
    int n  = i2 / 4096;
    int r1 = i2 - n*4096;
    int kt = r1 / 512;
    int r3 = r1 - kt*512;
    int ln = r3 >> 3, e = r3 & 7;
    int row = n*16 + (ln & 15);
    int col = kt*32 + (ln>>4)*8 + e;
    fcw[i2] = (row < VOC) ? f2bf(fcW[row*256 + col]) : (short)0;
  } else if (idx < NW0 + NW1 + NFC + 1024) {
    int i2 = idx - (NW0 + NW1 + NFC);
    b0[i2] = bih0[i2] + bhh0[i2];
  } else if (idx < NW0 + NW1 + NFC + 2048) {
    int i2 = idx - (NW0 + NW1 + NFC + 1024);
    b1[i2] = bih1[i2] + bhh1[i2];
  }
}

// 16 waves (4/SIMD): wave wv owns 16 gate-channels ch0=wv*16 for BOTH layers.
__global__ __launch_bounds__(1024, 4)
void lstm_kernel(const int* __restrict__ x, const float* __restrict__ emb,
                 const float* __restrict__ fcb,
                 const short* __restrict__ W0, const short* __restrict__ W1,
                 const short* __restrict__ FCW,
                 const float* __restrict__ b0, const float* __restrict__ b1,
                 unsigned* __restrict__ bar,
                 float* __restrict__ out)
{
  __shared__ __align__(16) short emb_s[36*136];
  __shared__ __align__(16) short h0_s[ROWS*264];
  __shared__ __align__(16) short h1_s[ROWS*264];
  __shared__ int   tok_s[ROWS];
  __shared__ float invlen_s[ROWS];

  const int tid  = threadIdx.x;
  const int lane = tid & 63;
  const int wv   = tid >> 6;      // 0..15
  const int l15  = lane & 15;
  const int l4   = lane >> 4;     // 0..3
  const int r0   = blockIdx.x * ROWS;
  const int ch0  = wv * 16;

  for (int i = tid; i < 36*128; i += 1024) {
    int r = i >> 7, c = i & 127;
    emb_s[r*136 + c] = f2bf(emb[i]);
  }
  for (int i = tid; i < ROWS*264; i += 1024) { h0_s[i] = 0; h1_s[i] = 0; }
  if (tid < ROWS) {
    int cnt = 0;
    for (int s = 0; s < SLEN; s++) cnt += (x[(r0+tid)*SLEN + s] != 0) ? 1 : 0;
    invlen_s[tid] = 1.0f / (float)cnt;
    tok_s[tid] = x[(r0+tid)*SLEN + 0];
  }
  __syncthreads();

  // invariant hoists
  const int ch = ch0 + l15;
  const short* w0base = W0 + wv*24576 + lane*8;   // + (G*12+kt)*512
  const short* w1base = W1 + wv*32768 + lane*8;   // + (G*16+kt)*512
  const short* fcbase = FCW + lane*8;             // + (n*8+kt)*512
  const float bi0 = b0[ch], bf0 = b0[256+ch], bg0 = b0[512+ch], bo0 = b0[768+ch];
  const float bi1 = b1[ch], bf1 = b1[256+ch], bg1 = b1[512+ch], bo1 = b1[768+ch];
  const bool  v2  = (l15 < 4);
  const float lb0 = fcb[l15], lb1 = fcb[16 + l15];
  const float lb2 = v2 ? fcb[32 + l15] : 0.f;

  float c0s[2][4] = {};
  float c1s[2][4] = {};
  float mloss[4] = {0.f,0.f,0.f,0.f};

  for (int t = 0; t < TLEN; t++) {
    // ---- phase-lock barrier (perf-only): keep all 128 blocks in step so
    // weight lines fetched by one block are L2-hits for the other 15 on its XCD.
    if (tid == 0 && t > 0) {
      __hip_atomic_fetch_add(bar, 1u, __ATOMIC_RELEASE, __HIP_MEMORY_SCOPE_AGENT);
      unsigned target = (unsigned)(NBLK * t);
      while (__hip_atomic_load(bar, __ATOMIC_ACQUIRE, __HIP_MEMORY_SCOPE_AGENT) < target)
        __builtin_amdgcn_s_sleep(2);
    }
    __syncthreads();

    int tokv[2];
    #pragma unroll
    for (int m = 0; m < 2; m++) tokv[m] = tok_s[m*16 + l15];

    // ================= Layer 0: gates = [e_t | h0] @ W0^T + b0 =================
    float hn0[2][4];
    {
      f32x4 acc[2][4] = {};
      #pragma unroll
      for (int kt = 0; kt < 12; kt++) {
        bf16x8 Bf[4];
        #pragma unroll
        for (int G = 0; G < 4; G++)
          Bf[G] = *(const bf16x8*)(w0base + (G*12 + kt)*512);
        bf16x8 Af[2];
        #pragma unroll
        for (int m = 0; m < 2; m++) {
          if (kt < 4) Af[m] = *(const bf16x8*)(emb_s + tokv[m]*136 + kt*32 + l4*8);
          else        Af[m] = *(const bf16x8*)(h0_s + (m*16 + l15)*264 + (kt-4)*32 + l4*8);
        }
        #pragma unroll
        for (int m = 0; m < 2; m++)
          #pragma unroll
          for (int G = 0; G < 4; G++)
            acc[m][G] = __builtin_amdgcn_mfma_f32_16x16x32_bf16(Af[m], Bf[G], acc[m][G], 0, 0, 0);
      }
      #pragma unroll
      for (int m = 0; m < 2; m++)
        #pragma unroll
        for (int j = 0; j < 4; j++) {
          float iv = fsig (acc[m][0][j] + bi0);
          float fv = fsig (acc[m][1][j] + bf0);
          float gv = ftanh(acc[m][2][j] + bg0);
          float ov = fsig (acc[m][3][j] + bo0);
          float c  = fv * c0s[m][j] + iv * gv;
          c0s[m][j] = c;
          hn0[m][j] = ov * ftanh(c);
        }
    }
    __syncthreads();   // b1: all waves done reading h0(t-1), tok(t)

    if (wv == 15 && lane < ROWS) tok_s[lane] = x[(r0+lane)*SLEN + t + 1];
    #pragma unroll
    for (int m = 0; m < 2; m++)
      #pragma unroll
      for (int j = 0; j < 4; j++)
        h0_s[(m*16 + l4*4 + j)*264 + ch] = f2bf(hn0[m][j]);
    __syncthreads();   // b2: h0(t) + tok(t+1) visible

    // ================= Layer 1: gates = [h0 | h1] @ W1^T + b1 =================
    float hn1[2][4];
    {
      f32x4 acc[2][4] = {};
      #pragma unroll
      for (int kt = 0; kt < 16; kt++) {
        bf16x8 Bf[4];
        #pragma unroll
        for (int G = 0; G < 4; G++)
          Bf[G] = *(const bf16x8*)(w1base + (G*16 + kt)*512);
        bf16x8 Af[2];
        #pragma unroll
        for (int m = 0; m < 2; m++) {
          if (kt < 8) Af[m] = *(const bf16x8*)(h0_s + (m*16 + l15)*264 + kt*32 + l4*8);
          else        Af[m] = *(const bf16x8*)(h1_s + (m*16 + l15)*264 + (kt-8)*32 + l4*8);
        }
        #pragma unroll
        for (int m = 0; m < 2; m++)
          #pragma unroll
          for (int G = 0; G < 4; G++)
            acc[m][G] = __builtin_amdgcn_mfma_f32_16x16x32_bf16(Af[m], Bf[G], acc[m][G], 0, 0, 0);
      }
      #pragma unroll
      for (int m = 0; m < 2; m++)
        #pragma unroll
        for (int j = 0; j < 4; j++) {
          float iv = fsig (acc[m][0][j] + bi1);
          float fv = fsig (acc[m][1][j] + bf1);
          float gv = ftanh(acc[m][2][j] + bg1);
          float ov = fsig (acc[m][3][j] + bo1);
          float c  = fv * c1s[m][j] + iv * gv;
          c1s[m][j] = c;
          hn1[m][j] = ov * ftanh(c);
        }
    }
    __syncthreads();   // b3: all waves done reading h1(t-1)

    #pragma unroll
    for (int m = 0; m < 2; m++)
      #pragma unroll
      for (int j = 0; j < 4; j++)
        h1_s[(m*16 + l4*4 + j)*264 + ch] = f2bf(hn1[m][j]);
    __syncthreads();   // b4: h1(t) visible

    // ===== FC + softmax + loss: waves 0-1 only =====
    if (wv < 2) {
      const int wr = wv * 16;
      f32x4 a3[3] = {};
      #pragma unroll
      for (int kt = 0; kt < 8; kt++) {
        bf16x8 Ah = *(const bf16x8*)(h1_s + (wr + l15)*264 + kt*32 + l4*8);
        #pragma unroll
        for (int n = 0; n < 3; n++) {
          bf16x8 Bf = *(const bf16x8*)(fcbase + (n*8 + kt)*512);
          a3[n] = __builtin_amdgcn_mfma_f32_16x16x32_bf16(Ah, Bf, a3[n], 0, 0, 0);
        }
      }
      #pragma unroll
      for (int j = 0; j < 4; j++) {
        float g0 = fmaxf(a3[0][j] + lb0, 0.f);
        float g1 = fmaxf(a3[1][j] + lb1, 0.f);
        float g2 = v2 ? fmaxf(a3[2][j] + lb2, 0.f) : -INFINITY;
        float mx = fmaxf(fmaxf(g0, g1), g2);
        #pragma unroll
        for (int k = 1; k < 16; k <<= 1) mx = fmaxf(mx, __shfl_xor(mx, k, 64));
        float e0 = __expf(g0 - mx), e1 = __expf(g1 - mx);
        float e2 = v2 ? __expf(g2 - mx) : 0.f;
        float sm = e0 + e1 + e2;
        #pragma unroll
        for (int k = 1; k < 16; k <<= 1) sm += __shfl_xor(sm, k, 64);
        float inv = 1.0f / sm;
        int row = wr + l4*4 + j;
        float* po = out + ((size_t)(r0 + row)*TLEN + t)*VOC;
        __builtin_nontemporal_store(e0 * inv, po + l15);
        __builtin_nontemporal_store(e1 * inv, po + 16 + l15);
        if (v2) __builtin_nontemporal_store(e2 * inv, po + 32 + l15);
        int tg = tok_s[row];                       // holds x[.., t+1]
        float sel = (tg < 16) ? g0 : ((tg < 32) ? g1 : g2);
        float ltg = __shfl(sel, (lane & 48) | (tg & 15), 64);
        float nll = mx + __logf(sm) - ltg;
        mloss[j] += (tg != 0) ? nll * invlen_s[row] : 0.f;
      }
    }
  } // t loop

  if (wv < 2 && l15 == 0) {
    float tot = 0.f;
    #pragma unroll
    for (int j = 0; j < 4; j++) {
      int row = wv*16 + l4*4 + j;
      __builtin_nontemporal_store(mloss[j], out + (size_t)MLOSS_OFF + r0 + row);
      tot += mloss[j];
    }
    atomicAdd(out + LOSS_OFF, tot * (1.0f/4096.0f));
  }
}

extern "C" void kernel_launch(void* const* d_in, const int* in_sizes, int n_in,
                              void* d_out, int out_size, void* d_ws, size_t ws_size,
                              hipStream_t stream) {
  const int*   x    = (const int*)  d_in[0];
  const float* emb  = (const float*)d_in[1];
  const float* Wih0 = (const float*)d_in[2];
  const float* Whh0 = (const float*)d_in[3];
  const float* bih0 = (const float*)d_in[4];
  const float* bhh0 = (const float*)d_in[5];
  const float* Wih1 = (const float*)d_in[6];
  const float* Whh1 = (const float*)d_in[7];
  const float* bih1 = (const float*)d_in[8];
  const float* bhh1 = (const float*)d_in[9];
  const float* fcW  = (const float*)d_in[10];
  const float* fcb  = (const float*)d_in[11];

  short* w0  = (short*)((char*)d_ws + WS_W0);
  short* w1  = (short*)((char*)d_ws + WS_W1);
  short* fcw = (short*)((char*)d_ws + WS_FC);
  float* b0  = (float*)((char*)d_ws + WS_B0);
  float* b1  = (float*)((char*)d_ws + WS_B1);
  unsigned* bar = (unsigned*)((char*)d_ws + WS_BAR);
  float* out = (float*)d_out;

  prep_kernel<<<3641, 256, 0, stream>>>(Wih0, Whh0, bih0, bhh0, Wih1, Whh1,
                                        bih1, bhh1, fcW, w0, w1, fcw, b0, b1, bar, out);
  lstm_kernel<<<NBLK, 1024, 0, stream>>>(x, emb, fcb, w0, w1, fcw, b0, b1, bar, out);
}

// Round 4
// 6940.871 us; speedup vs baseline: 1.8725x; 1.8725x over previous
//
#include <hip/hip_runtime.h>

typedef float f32x4 __attribute__((ext_vector_type(4)));
typedef short bf16x8 __attribute__((ext_vector_type(8)));

#define SLEN 128
#define TLEN 127
#define VOC 36
#define NPROBS (4096*127*36)
#define MLOSS_OFF NPROBS
#define LOSS_OFF (NPROBS + 4096)

// packed weights (shorts): W0p[wv16][G4][kt12][512], W1p[wv16][G4][kt16][512], FCp[n3][kt8][512]
#define WS_W0 0
#define WS_W1 786432
#define WS_FC 1835008
#define WS_B0 1859584
#define WS_B1 1863680
#define NW0 393216
#define NW1 524288
#define NFC 12288

// pipeline buffers
#define WS_H0  2097152              // short[16][2][8][256][32] = 4 MB
#define WS_H1  6291456              // same, 4 MB
#define WS_CTR 10485760             // 16 groups x 96 uints (384B each)
#define WS_NEEDED 10491904

#define GRP_STRIDE 131072           // shorts per group (2 slots x 65536)
#define SLOT_STRIDE 65536           // shorts per slot (8*256*32)

__device__ __forceinline__ short f2bf(float f){
  unsigned u = __float_as_uint(f);
  u += 0x7fffu + ((u >> 16) & 1u);
  return (short)(u >> 16);
}
__device__ __forceinline__ float fsig(float x){ return 1.0f/(1.0f + __expf(-x)); }
__device__ __forceinline__ float ftanh(float x){ return 1.0f - 2.0f/(1.0f + __expf(2.0f*x)); }

__device__ __forceinline__ void spin_ge(const unsigned* p, unsigned v){
  while (__hip_atomic_load(p, __ATOMIC_ACQUIRE, __HIP_MEMORY_SCOPE_AGENT) < v)
    __builtin_amdgcn_s_sleep(2);
}

__global__ void prep_kernel(const float* __restrict__ Wih0, const float* __restrict__ Whh0,
                            const float* __restrict__ bih0, const float* __restrict__ bhh0,
                            const float* __restrict__ Wih1, const float* __restrict__ Whh1,
                            const float* __restrict__ bih1, const float* __restrict__ bhh1,
                            const float* __restrict__ fcW,
                            short* __restrict__ w0, short* __restrict__ w1, short* __restrict__ fcw,
                            float* __restrict__ b0, float* __restrict__ b1,
                            unsigned* __restrict__ ctr,
                            float* __restrict__ out)
{
  int idx = blockIdx.x*256 + threadIdx.x;
  if (idx == 0) out[LOSS_OFF] = 0.0f;
  if (idx < NW0) {
    int wv = idx / 24576;
    int r1 = idx - wv*24576;
    int G  = r1 / 6144;
    int r2 = r1 - G*6144;
    int kt = r2 / 512;
    int r3 = r2 - kt*512;
    int ln = r3 >> 3, e = r3 & 7;
    int row = G*256 + wv*16 + (ln & 15);
    int col = kt*32 + (ln>>4)*8 + e;
    float v = (col < 128) ? Wih0[row*128 + col] : Whh0[row*256 + (col-128)];
    w0[idx] = f2bf(v);
  } else if (idx < NW0 + NW1) {
    int i2 = idx - NW0;
    int wv = i2 / 32768;
    int r1 = i2 - wv*32768;
    int G  = r1 / 8192;
    int r2 = r1 - G*8192;
    int kt = r2 / 512;
    int r3 = r2 - kt*512;
    int ln = r3 >> 3, e = r3 & 7;
    int row = G*256 + wv*16 + (ln & 15);
    int col = kt*32 + (ln>>4)*8 + e;
    float v = (col < 256) ? Wih1[row*256 + col] : Whh1[row*256 + (col-256)];
    w1[i2] = f2bf(v);
  } else if (idx < NW0 + NW1 + NFC) {
    int i2 = idx - (NW0 + NW1);
    int n  = i2 / 4096;
    int r1 = i2 - n*4096;
    int kt = r1 / 512;
    int r3 = r1 - kt*512;
    int ln = r3 >> 3, e = r3 & 7;
    int row = n*16 + (ln & 15);
    int col = kt*32 + (ln>>4)*8 + e;
    fcw[i2] = (row < VOC) ? f2bf(fcW[row*256 + col]) : (short)0;
  } else if (idx < NW0 + NW1 + NFC + 1024) {
    int i2 = idx - (NW0 + NW1 + NFC);
    b0[i2] = bih0[i2] + bhh0[i2];
  } else if (idx < NW0 + NW1 + NFC + 2048) {
    int i2 = idx - (NW0 + NW1 + NFC + 1024);
    b1[i2] = bih1[i2] + bhh1[i2];
  } else if (ctr && idx < NW0 + NW1 + NFC + 2048 + 1536) {
    ctr[idx - (NW0 + NW1 + NFC + 2048)] = 0u;
  }
}

// ===================== persistent pipeline kernel =====================
// 256 blocks, 1/CU. group g = (b&7) + 8*(b>>7); q = (b>>3)&15.
// q<8: L0 role (channels [32q,32q+32) of layer0). q>=8: L1 role + FC.
__global__ __launch_bounds__(1024, 4)
void lstm_pipe(const int* __restrict__ x, const float* __restrict__ emb,
               const float* __restrict__ fcb,
               const short* __restrict__ W0, const short* __restrict__ W1,
               const short* __restrict__ FCW,
               const float* __restrict__ b0, const float* __restrict__ b1,
               short* __restrict__ h0b, short* __restrict__ h1b,
               unsigned* __restrict__ ctr,
               float* __restrict__ out)
{
  extern __shared__ short lds[];
  const int tid  = threadIdx.x;
  const int lane = tid & 63;
  const int w    = tid >> 6;          // wave 0..15
  const int l15  = lane & 15;
  const int l4   = lane >> 4;

  const int b   = blockIdx.x;
  const int g   = (b & 7) + 8*(b >> 7);
  const int q   = (b >> 3) & 15;

  unsigned* c_h0 = ctr + g*96;
  unsigned* c_h1 = ctr + g*96 + 32;
  unsigned* c_fc = ctr + g*96 + 64;

  short* grp_h0 = h0b + g*GRP_STRIDE;
  short* grp_h1 = h1b + g*GRP_STRIDE;

  if (q < 8) {
    // ======================= L0 role =======================
    short* Wl   = lds;                  // [8 nt][12 kt][512]
    short* embs = lds + 49152;          // [36][136]
    // stage W0 slice
    for (int idx = tid; idx < 49152; idx += 1024) {
      int nt = idx / 6144;
      int r  = idx - nt*6144;
      int kt = r >> 9, e = r & 511;
      Wl[idx] = W0[(((2*q + (nt&1))*4 + (nt>>1))*12 + kt)*512 + e];
    }
    for (int i = tid; i < 36*128; i += 1024) {
      int r = i >> 7, c = i & 127;
      embs[r*136 + c] = f2bf(emb[i]);
    }
    // zero h0(-1) slice (slot 1)
    for (int i = tid; i < 8192; i += 1024)
      grp_h0[SLOT_STRIDE + q*8192 + i] = 0;
    __syncthreads();
    if (tid == 0) {
      __threadfence();
      __hip_atomic_fetch_add(c_h0, 1u, __ATOMIC_RELEASE, __HIP_MEMORY_SCOPE_AGENT);
    }

    const int ch = 32*q + l15;
    const float bi0 = b0[ch],      bf0 = b0[256+ch],      bg0 = b0[512+ch],      bo0 = b0[768+ch];
    const float bi1 = b0[16+ch],   bf1 = b0[272+ch],      bg1 = b0[528+ch],      bo1 = b0[784+ch];
    float cs[2][4] = {};

    const int rowA = g*256 + 16*w + l15;       // A-operand row for this lane

    for (int t = 0; t < TLEN; t++) {
      if (tid == 0) {
        spin_ge(c_h0, 8u*(t+1));
        if (t >= 2) spin_ge(c_h1, 8u*t);
        __threadfence();                        // acquire: invalidate L1
      }
      __syncthreads();

      int tok = x[(size_t)rowA*SLEN + t];
      const short* hsrc = grp_h0 + ((t^1)&1)*SLOT_STRIDE;

      f32x4 acc[8] = {};
      #pragma unroll
      for (int kt = 0; kt < 12; kt++) {
        bf16x8 Af;
        if (kt < 4) Af = *(const bf16x8*)(embs + tok*136 + kt*32 + l4*8);
        else        Af = *(const bf16x8*)(hsrc + (kt-4)*8192 + (16*w + l15)*32 + l4*8);
        #pragma unroll
        for (int nt = 0; nt < 8; nt++) {
          bf16x8 Bf = *(const bf16x8*)(Wl + (nt*12 + kt)*512 + lane*8);
          acc[nt] = __builtin_amdgcn_mfma_f32_16x16x32_bf16(Af, Bf, acc[nt], 0, 0, 0);
        }
      }
      short* hdst = grp_h0 + (t&1)*SLOT_STRIDE + q*8192;
      #pragma unroll
      for (int j = 0; j < 4; j++) {
        float i0 = fsig (acc[0][j] + bi0);
        float f0 = fsig (acc[2][j] + bf0);
        float g0 = ftanh(acc[4][j] + bg0);
        float o0 = fsig (acc[6][j] + bo0);
        float c0 = f0 * cs[0][j] + i0 * g0;
        cs[0][j] = c0;
        hdst[(16*w + 4*l4 + j)*32 + l15] = f2bf(o0 * ftanh(c0));
        float i1 = fsig (acc[1][j] + bi1);
        float f1 = fsig (acc[3][j] + bf1);
        float g1 = ftanh(acc[5][j] + bg1);
        float o1 = fsig (acc[7][j] + bo1);
        float c1 = f1 * cs[1][j] + i1 * g1;
        cs[1][j] = c1;
        hdst[(16*w + 4*l4 + j)*32 + 16 + l15] = f2bf(o1 * ftanh(c1));
      }
      __syncthreads();                           // drains stores (vmcnt0)
      if (tid == 0) {
        __threadfence();                         // release: wb L2
        __hip_atomic_fetch_add(c_h0, 1u, __ATOMIC_RELEASE, __HIP_MEMORY_SCOPE_AGENT);
      }
    }
  } else {
    // ======================= L1 + FC role =======================
    const int q8 = q - 8;
    short* Wl = lds;                    // [8 nt][16 kt][512]
    float* invlen_l = (float*)(lds + 65536);   // [32]
    for (int idx = tid; idx < 65536; idx += 1024) {
      int nt = idx / 8192;
      int r  = idx - nt*8192;
      int kt = r >> 9, e = r & 511;
      Wl[idx] = W1[(((2*q8 + (nt&1))*4 + (nt>>1))*16 + kt)*512 + e];
    }
    for (int i = tid; i < 8192; i += 1024)
      grp_h1[SLOT_STRIDE + q8*8192 + i] = 0;
    if (tid < 32) {
      int row = g*256 + 32*q8 + tid;
      int cnt = 0;
      for (int s = 0; s < SLEN; s++) cnt += (x[(size_t)row*SLEN + s] != 0) ? 1 : 0;
      invlen_l[tid] = 1.0f / (float)cnt;
    }
    __syncthreads();
    if (tid == 0) {
      __threadfence();
      __hip_atomic_fetch_add(c_h1, 1u, __ATOMIC_RELEASE, __HIP_MEMORY_SCOPE_AGENT);
    }

    const int ch = 32*q8 + l15;
    const float bi0 = b1[ch],      bf0 = b1[256+ch],      bg0 = b1[512+ch],      bo0 = b1[768+ch];
    const float bi1 = b1[16+ch],   bf1 = b1[272+ch],      bg1 = b1[528+ch],      bo1 = b1[784+ch];
    float cs[2][4] = {};
    float mloss[4] = {0.f,0.f,0.f,0.f};
    const bool  v2  = (l15 < 4);
    const float lb0 = fcb[l15], lb1 = fcb[16 + l15];
    const float lb2 = v2 ? fcb[32 + l15] : 0.f;
    const short* fcbase = FCW + lane*8;

    for (int t = 0; t < TLEN; t++) {
      if (tid == 0) {
        spin_ge(c_h0, 8u*(t+2));
        spin_ge(c_h1, 8u*(t+1));
        if (t >= 2) spin_ge(c_fc, 8u*(t-1));
        __threadfence();
      }
      __syncthreads();

      const short* h0src = grp_h0 + (t&1)*SLOT_STRIDE;
      const short* h1src = grp_h1 + ((t^1)&1)*SLOT_STRIDE;

      f32x4 acc[8] = {};
      #pragma unroll
      for (int kt = 0; kt < 16; kt++) {
        bf16x8 Af;
        if (kt < 8) Af = *(const bf16x8*)(h0src + kt*8192     + (16*w + l15)*32 + l4*8);
        else        Af = *(const bf16x8*)(h1src + (kt-8)*8192 + (16*w + l15)*32 + l4*8);
        #pragma unroll
        for (int nt = 0; nt < 8; nt++) {
          bf16x8 Bf = *(const bf16x8*)(Wl + (nt*16 + kt)*512 + lane*8);
          acc[nt] = __builtin_amdgcn_mfma_f32_16x16x32_bf16(Af, Bf, acc[nt], 0, 0, 0);
        }
      }
      short* hdst = grp_h1 + (t&1)*SLOT_STRIDE + q8*8192;
      #pragma unroll
      for (int j = 0; j < 4; j++) {
        float i0 = fsig (acc[0][j] + bi0);
        float f0 = fsig (acc[2][j] + bf0);
        float g0 = ftanh(acc[4][j] + bg0);
        float o0 = fsig (acc[6][j] + bo0);
        float c0 = f0 * cs[0][j] + i0 * g0;
        cs[0][j] = c0;
        hdst[(16*w + 4*l4 + j)*32 + l15] = f2bf(o0 * ftanh(c0));
        float i1 = fsig (acc[1][j] + bi1);
        float f1 = fsig (acc[3][j] + bf1);
        float g1 = ftanh(acc[5][j] + bg1);
        float o1 = fsig (acc[7][j] + bo1);
        float c1 = f1 * cs[1][j] + i1 * g1;
        cs[1][j] = c1;
        hdst[(16*w + 4*l4 + j)*32 + 16 + l15] = f2bf(o1 * ftanh(c1));
      }
      __syncthreads();
      if (tid == 0) {
        __threadfence();
        __hip_atomic_fetch_add(c_h1, 1u, __ATOMIC_RELEASE, __HIP_MEMORY_SCOPE_AGENT);
        spin_ge(c_h1, 8u*(t+2));                 // siblings' h1(t)
        __threadfence();
      }
      __syncthreads();

      // ---- FC + softmax + loss (waves 0-1: 32 rows of this block) ----
      if (w < 2) {
        const short* h1cur = grp_h1 + (t&1)*SLOT_STRIDE;
        f32x4 a3[3] = {};
        #pragma unroll
        for (int kt = 0; kt < 8; kt++) {
          bf16x8 Ah = *(const bf16x8*)(h1cur + kt*8192 + (32*q8 + 16*w + l15)*32 + l4*8);
          #pragma unroll
          for (int n = 0; n < 3; n++) {
            bf16x8 Bf = *(const bf16x8*)(fcbase + (n*8 + kt)*512);
            a3[n] = __builtin_amdgcn_mfma_f32_16x16x32_bf16(Ah, Bf, a3[n], 0, 0, 0);
          }
        }
        #pragma unroll
        for (int j = 0; j < 4; j++) {
          float g0 = fmaxf(a3[0][j] + lb0, 0.f);
          float g1 = fmaxf(a3[1][j] + lb1, 0.f);
          float g2 = v2 ? fmaxf(a3[2][j] + lb2, 0.f) : -INFINITY;
          float mx = fmaxf(fmaxf(g0, g1), g2);
          #pragma unroll
          for (int k = 1; k < 16; k <<= 1) mx = fmaxf(mx, __shfl_xor(mx, k, 64));
          float e0 = __expf(g0 - mx), e1 = __expf(g1 - mx);
          float e2 = v2 ? __expf(g2 - mx) : 0.f;
          float sm = e0 + e1 + e2;
          #pragma unroll
          for (int k = 1; k < 16; k <<= 1) sm += __shfl_xor(sm, k, 64);
          float inv = 1.0f / sm;
          int lrow = 16*w + 4*l4 + j;
          int grow = g*256 + 32*q8 + lrow;
          float* po = out + ((size_t)grow*TLEN + t)*VOC;
          __builtin_nontemporal_store(e0 * inv, po + l15);
          __builtin_nontemporal_store(e1 * inv, po + 16 + l15);
          if (v2) __builtin_nontemporal_store(e2 * inv, po + 32 + l15);
          int tg = x[(size_t)grow*SLEN + t + 1];
          float sel = (tg < 16) ? g0 : ((tg < 32) ? g1 : g2);
          float ltg = __shfl(sel, (lane & 48) | (tg & 15), 64);
          float nll = mx + __logf(sm) - ltg;
          mloss[j] += (tg != 0) ? nll * invlen_l[lrow] : 0.f;
        }
      }
      __syncthreads();                            // FC loads retired (vmcnt0)
      if (tid == 0)
        __hip_atomic_fetch_add(c_fc, 1u, __ATOMIC_RELAXED, __HIP_MEMORY_SCOPE_AGENT);
    }

    if (w < 2 && l15 == 0) {
      float tot = 0.f;
      #pragma unroll
      for (int j = 0; j < 4; j++) {
        int grow = g*256 + 32*q8 + 16*w + 4*l4 + j;
        __builtin_nontemporal_store(mloss[j], out + (size_t)MLOSS_OFF + grow);
        tot += mloss[j];
      }
      atomicAdd(out + LOSS_OFF, tot * (1.0f/4096.0f));
    }
  }
}

// ===================== fallback (R2 kernel, 9.6 ms) =====================
__global__ __launch_bounds__(1024, 4)
void lstm_small(const int* __restrict__ x, const float* __restrict__ emb,
                const float* __restrict__ fcb,
                const short* __restrict__ W0, const short* __restrict__ W1,
                const short* __restrict__ FCW,
                const float* __restrict__ b0, const float* __restrict__ b1,
                float* __restrict__ out)
{
  __shared__ __align__(16) short emb_s[36*136];
  __shared__ __align__(16) short h0_s[32*264];
  __shared__ __align__(16) short h1_s[32*264];
  __shared__ int   tok_s[32];
  __shared__ float invlen_s[32];

  const int tid  = threadIdx.x;
  const int lane = tid & 63;
  const int wv   = tid >> 6;
  const int l15  = lane & 15;
  const int l4   = lane >> 4;
  const int r0   = blockIdx.x * 32;

  for (int i = tid; i < 36*128; i += 1024) {
    int r = i >> 7, c = i & 127;
    emb_s[r*136 + c] = f2bf(emb[i]);
  }
  for (int i = tid; i < 32*264; i += 1024) { h0_s[i] = 0; h1_s[i] = 0; }
  if (tid < 32) {
    int cnt = 0;
    for (int s = 0; s < SLEN; s++) cnt += (x[(r0+tid)*SLEN + s] != 0) ? 1 : 0;
    invlen_s[tid] = 1.0f / (float)cnt;
    tok_s[tid] = x[(r0+tid)*SLEN + 0];
  }
  __syncthreads();

  const int ch = wv*16 + l15;
  const short* w0base = W0 + wv*24576 + lane*8;
  const short* w1base = W1 + wv*32768 + lane*8;
  const short* fcbase = FCW + lane*8;
  const float bi0 = b0[ch], bf0 = b0[256+ch], bg0 = b0[512+ch], bo0 = b0[768+ch];
  const float bi1 = b1[ch], bf1 = b1[256+ch], bg1 = b1[512+ch], bo1 = b1[768+ch];
  const bool  v2  = (l15 < 4);
  const float lb0 = fcb[l15], lb1 = fcb[16 + l15];
  const float lb2 = v2 ? fcb[32 + l15] : 0.f;

  float c0s[2][4] = {};
  float c1s[2][4] = {};
  float mloss[4] = {0.f,0.f,0.f,0.f};

  for (int t = 0; t < TLEN; t++) {
    int tokv[2];
    #pragma unroll
    for (int m = 0; m < 2; m++) tokv[m] = tok_s[m*16 + l15];
    float hn0[2][4];
    {
      f32x4 acc[2][4] = {};
      #pragma unroll
      for (int kt = 0; kt < 12; kt++) {
        bf16x8 Bf[4];
        #pragma unroll
        for (int G = 0; G < 4; G++) Bf[G] = *(const bf16x8*)(w0base + (G*12 + kt)*512);
        bf16x8 Af[2];
        #pragma unroll
        for (int m = 0; m < 2; m++) {
          if (kt < 4) Af[m] = *(const bf16x8*)(emb_s + tokv[m]*136 + kt*32 + l4*8);
          else        Af[m] = *(const bf16x8*)(h0_s + (m*16 + l15)*264 + (kt-4)*32 + l4*8);
        }
        #pragma unroll
        for (int m = 0; m < 2; m++)
          #pragma unroll
          for (int G = 0; G < 4; G++)
            acc[m][G] = __builtin_amdgcn_mfma_f32_16x16x32_bf16(Af[m], Bf[G], acc[m][G], 0, 0, 0);
      }
      #pragma unroll
      for (int m = 0; m < 2; m++)
        #pragma unroll
        for (int j = 0; j < 4; j++) {
          float iv = fsig (acc[m][0][j] + bi0);
          float fv = fsig (acc[m][1][j] + bf0);
          float gv = ftanh(acc[m][2][j] + bg0);
          float ov = fsig (acc[m][3][j] + bo0);
          float c  = fv * c0s[m][j] + iv * gv;
          c0s[m][j] = c;
          hn0[m][j] = ov * ftanh(c);
        }
    }
    __syncthreads();
    if (wv == 15 && lane < 32) tok_s[lane] = x[(r0+lane)*SLEN + t + 1];
    #pragma unroll
    for (int m = 0; m < 2; m++)
      #pragma unroll
      for (int j = 0; j < 4; j++)
        h0_s[(m*16 + l4*4 + j)*264 + ch] = f2bf(hn0[m][j]);
    __syncthreads();
    float hn1[2][4];
    {
      f32x4 acc[2][4] = {};
      #pragma unroll
      for (int kt = 0; kt < 16; kt++) {
        bf16x8 Bf[4];
        #pragma unroll
        for (int G = 0; G < 4; G++) Bf[G] = *(const bf16x8*)(w1base + (G*16 + kt)*512);
        bf16x8 Af[2];
        #pragma unroll
        for (int m = 0; m < 2; m++) {
          if (kt < 8) Af[m] = *(const bf16x8*)(h0_s + (m*16 + l15)*264 + kt*32 + l4*8);
          else        Af[m] = *(const bf16x8*)(h1_s + (m*16 + l15)*264 + (kt-8)*32 + l4*8);
        }
        #pragma unroll
        for (int m = 0; m < 2; m++)
          #pragma unroll
          for (int G = 0; G < 4; G++)
            acc[m][G] = __builtin_amdgcn_mfma_f32_16x16x32_bf16(Af[m], Bf[G], acc[m][G], 0, 0, 0);
      }
      #pragma unroll
      for (int m = 0; m < 2; m++)
        #pragma unroll
        for (int j = 0; j < 4; j++) {
          float iv = fsig (acc[m][0][j] + bi1);
          float fv = fsig (acc[m][1][j] + bf1);
          float gv = ftanh(acc[m][2][j] + bg1);
          float ov = fsig (acc[m][3][j] + bo1);
          float c  = fv * c1s[m][j] + iv * gv;
          c1s[m][j] = c;
          hn1[m][j] = ov * ftanh(c);
        }
    }
    __syncthreads();
    #pragma unroll
    for (int m = 0; m < 2; m++)
      #pragma unroll
      for (int j = 0; j < 4; j++)
        h1_s[(m*16 + l4*4 + j)*264 + ch] = f2bf(hn1[m][j]);
    __syncthreads();
    if (wv < 2) {
      const int wr = wv * 16;
      f32x4 a3[3] = {};
      #pragma unroll
      for (int kt = 0; kt < 8; kt++) {
        bf16x8 Ah = *(const bf16x8*)(h1_s + (wr + l15)*264 + kt*32 + l4*8);
        #pragma unroll
        for (int n = 0; n < 3; n++) {
          bf16x8 Bf = *(const bf16x8*)(fcbase + (n*8 + kt)*512);
          a3[n] = __builtin_amdgcn_mfma_f32_16x16x32_bf16(Ah, Bf, a3[n], 0, 0, 0);
        }
      }
      #pragma unroll
      for (int j = 0; j < 4; j++) {
        float g0 = fmaxf(a3[0][j] + lb0, 0.f);
        float g1 = fmaxf(a3[1][j] + lb1, 0.f);
        float g2 = v2 ? fmaxf(a3[2][j] + lb2, 0.f) : -INFINITY;
        float mx = fmaxf(fmaxf(g0, g1), g2);
        #pragma unroll
        for (int k = 1; k < 16; k <<= 1) mx = fmaxf(mx, __shfl_xor(mx, k, 64));
        float e0 = __expf(g0 - mx), e1 = __expf(g1 - mx);
        float e2 = v2 ? __expf(g2 - mx) : 0.f;
        float sm = e0 + e1 + e2;
        #pragma unroll
        for (int k = 1; k < 16; k <<= 1) sm += __shfl_xor(sm, k, 64);
        float inv = 1.0f / sm;
        int row = wr + l4*4 + j;
        float* po = out + ((size_t)(r0 + row)*TLEN + t)*VOC;
        __builtin_nontemporal_store(e0 * inv, po + l15);
        __builtin_nontemporal_store(e1 * inv, po + 16 + l15);
        if (v2) __builtin_nontemporal_store(e2 * inv, po + 32 + l15);
        int tg = tok_s[row];
        float sel = (tg < 16) ? g0 : ((tg < 32) ? g1 : g2);
        float ltg = __shfl(sel, (lane & 48) | (tg & 15), 64);
        float nll = mx + __logf(sm) - ltg;
        mloss[j] += (tg != 0) ? nll * invlen_s[row] : 0.f;
      }
    }
  }
  if (wv < 2 && l15 == 0) {
    float tot = 0.f;
    #pragma unroll
    for (int j = 0; j < 4; j++) {
      int row = wv*16 + l4*4 + j;
      __builtin_nontemporal_store(mloss[j], out + (size_t)MLOSS_OFF + r0 + row);
      tot += mloss[j];
    }
    atomicAdd(out + LOSS_OFF, tot * (1.0f/4096.0f));
  }
}

extern "C" void kernel_launch(void* const* d_in, const int* in_sizes, int n_in,
                              void* d_out, int out_size, void* d_ws, size_t ws_size,
                              hipStream_t stream) {
  const int*   x    = (const int*)  d_in[0];
  const float* emb  = (const float*)d_in[1];
  const float* Wih0 = (const float*)d_in[2];
  const float* Whh0 = (const float*)d_in[3];
  const float* bih0 = (const float*)d_in[4];
  const float* bhh0 = (const float*)d_in[5];
  const float* Wih1 = (const float*)d_in[6];
  const float* Whh1 = (const float*)d_in[7];
  const float* bih1 = (const float*)d_in[8];
  const float* bhh1 = (const float*)d_in[9];
  const float* fcW  = (const float*)d_in[10];
  const float* fcb  = (const float*)d_in[11];

  short* w0  = (short*)((char*)d_ws + WS_W0);
  short* w1  = (short*)((char*)d_ws + WS_W1);
  short* fcw = (short*)((char*)d_ws + WS_FC);
  float* b0  = (float*)((char*)d_ws + WS_B0);
  float* b1  = (float*)((char*)d_ws + WS_B1);
  float* out = (float*)d_out;

  bool big = (ws_size >= (size_t)WS_NEEDED);
  static int lds_ok = -1;
  if (big && lds_ok < 0) {
    hipError_t e = hipFuncSetAttribute((const void*)lstm_pipe,
                     hipFuncAttributeMaxDynamicSharedMemorySize, 131328);
    lds_ok = (e == hipSuccess) ? 1 : 0;
  }
  bool use_pipe = big && (lds_ok == 1);

  short*    h0bp = (short*)((char*)d_ws + WS_H0);
  short*    h1bp = (short*)((char*)d_ws + WS_H1);
  unsigned* ctr  = use_pipe ? (unsigned*)((char*)d_ws + WS_CTR) : nullptr;

  prep_kernel<<<3648, 256, 0, stream>>>(Wih0, Whh0, bih0, bhh0, Wih1, Whh1,
                                        bih1, bhh1, fcW, w0, w1, fcw, b0, b1, ctr, out);
  if (use_pipe) {
    lstm_pipe<<<256, 1024, 131328, stream>>>(x, emb, fcb, w0, w1, fcw, b0, b1,
                                             h0bp, h1bp, ctr, out);
  } else {
    lstm_small<<<128, 1024, 0, stream>>>(x, emb, fcb, w0, w1, fcw, b0, b1, out);
  }
}

// Round 5
// 3725.295 us; speedup vs baseline: 3.4889x; 1.8632x over previous
//
#include <hip/hip_runtime.h>

typedef float f32x4 __attribute__((ext_vector_type(4)));
typedef short bf16x8 __attribute__((ext_vector_type(8)));

#define SLEN 128
#define TLEN 127
#define VOC 36
#define NPROBS (4096*127*36)
#define MLOSS_OFF NPROBS
#define LOSS_OFF (NPROBS + 4096)

// packed weights (shorts): W0p[q16][G4][kt12][512], W1p[q16][G4][kt16][512], FCp[n3][kt8][512]
#define WS_W0 0
#define WS_W1 786432
#define WS_FC 1835008
#define WS_B0 1859584
#define WS_B1 1863680
#define NW0 393216
#define NW1 524288
#define NFC 12288

// pipeline buffers
#define WS_H0  2097152              // short[16 grp][2 slot][8 ktile][256 row][32 ch] = 4 MB
#define WS_H1  6291456              // same
#define WS_CTR 10485760             // 16 groups x 96 uints
#define WS_NEEDED 10491904

#define GRP 131072                  // shorts per group (2 slots)
#define SLOT 65536                  // shorts per slot

__device__ __forceinline__ short f2bf(float f){
  unsigned u = __float_as_uint(f);
  u += 0x7fffu + ((u >> 16) & 1u);
  return (short)(u >> 16);
}
__device__ __forceinline__ float fsig(float x){ return 1.0f/(1.0f + __expf(-x)); }
__device__ __forceinline__ float ftanh(float x){ return 1.0f - 2.0f/(1.0f + __expf(2.0f*x)); }

__device__ __forceinline__ void spin_ge(const unsigned* p, unsigned v){
  while (__hip_atomic_load(p, __ATOMIC_ACQUIRE, __HIP_MEMORY_SCOPE_AGENT) < v)
    __builtin_amdgcn_s_sleep(2);
}

__global__ void prep_kernel(const float* __restrict__ Wih0, const float* __restrict__ Whh0,
                            const float* __restrict__ bih0, const float* __restrict__ bhh0,
                            const float* __restrict__ Wih1, const float* __restrict__ Whh1,
                            const float* __restrict__ bih1, const float* __restrict__ bhh1,
                            const float* __restrict__ fcW,
                            short* __restrict__ w0, short* __restrict__ w1, short* __restrict__ fcw,
                            float* __restrict__ b0, float* __restrict__ b1,
                            unsigned* __restrict__ ctr,
                            float* __restrict__ out)
{
  int idx = blockIdx.x*256 + threadIdx.x;
  if (idx == 0) out[LOSS_OFF] = 0.0f;
  if (idx < NW0) {
    int wv = idx / 24576;
    int r1 = idx - wv*24576;
    int G  = r1 / 6144;
    int r2 = r1 - G*6144;
    int kt = r2 / 512;
    int r3 = r2 - kt*512;
    int ln = r3 >> 3, e = r3 & 7;
    int row = G*256 + wv*16 + (ln & 15);
    int col = kt*32 + (ln>>4)*8 + e;
    float v = (col < 128) ? Wih0[row*128 + col] : Whh0[row*256 + (col-128)];
    w0[idx] = f2bf(v);
  } else if (idx < NW0 + NW1) {
    int i2 = idx - NW0;
    int wv = i2 / 32768;
    int r1 = i2 - wv*32768;
    int G  = r1 / 8192;
    int r2 = r1 - G*8192;
    int kt = r2 / 512;
    int r3 = r2 - kt*512;
    int ln = r3 >> 3, e = r3 & 7;
    int row = G*256 + wv*16 + (ln & 15);
    int col = kt*32 + (ln>>4)*8 + e;
    float v = (col < 256) ? Wih1[row*256 + col] : Whh1[row*256 + (col-256)];
    w1[i2] = f2bf(v);
  } else if (idx < NW0 + NW1 + NFC) {
    int i2 = idx - (NW0 + NW1);
    int n  = i2 / 4096;
    int r1 = i2 - n*4096;
    int kt = r1 / 512;
    int r3 = r1 - kt*512;
    int ln = r3 >> 3, e = r3 & 7;
    int row = n*16 + (ln & 15);
    int col = kt*32 + (ln>>4)*8 + e;
    fcw[i2] = (row < VOC) ? f2bf(fcW[row*256 + col]) : (short)0;
  } else if (idx < NW0 + NW1 + NFC + 1024) {
    int i2 = idx - (NW0 + NW1 + NFC);
    b0[i2] = bih0[i2] + bhh0[i2];
  } else if (idx < NW0 + NW1 + NFC + 2048) {
    int i2 = idx - (NW0 + NW1 + NFC + 1024);
    b1[i2] = bih1[i2] + bhh1[i2];
  } else if (ctr && idx < NW0 + NW1 + NFC + 2048 + 1536) {
    ctr[idx - (NW0 + NW1 + NFC + 2048)] = 0u;
  }
}

// ============ merged-role persistent kernel: 1 rendezvous per tick ============
// 256 blocks, 1/CU. g = (b&7)+8*(b>>7), q = (b>>3)&15.
// Block q holds channels [16q,16q+16) of BOTH layers.
// Tick t: waves 0-7 -> h0(t); waves 8-15 -> h1(t-1); wave 7 also FC(t-2).
__global__ __launch_bounds__(1024, 4)
void lstm_fuse(const int* __restrict__ x, const float* __restrict__ emb,
               const float* __restrict__ fcb,
               const short* __restrict__ W0, const short* __restrict__ W1,
               const short* __restrict__ FCW,
               const float* __restrict__ b0, const float* __restrict__ b1,
               short* __restrict__ h0b, short* __restrict__ h1b,
               unsigned* __restrict__ ctr,
               float* __restrict__ out)
{
  extern __shared__ short lds[];
  short* Wl0  = lds;            // 24576 shorts (48 KB)
  short* Wl1  = lds + 24576;    // 32768 shorts (64 KB)
  short* fcs  = lds + 57344;    // 12288 shorts (24 KB)
  short* embs = lds + 69632;    // 36*136 = 4896 shorts
  float* invlen_l = (float*)(lds + 74528); // 16 floats

  const int tid  = threadIdx.x;
  const int lane = tid & 63;
  const int w    = tid >> 6;      // 0..15
  const int l15  = lane & 15;
  const int l4   = lane >> 4;

  const int b = blockIdx.x;
  const int g = (b & 7) + 8*(b >> 7);
  const int q = (b >> 3) & 15;

  unsigned* cc  = ctr + g*96;
  short* gh0 = h0b + g*GRP;
  short* gh1 = h1b + g*GRP;

  // ---- prologue: stage LDS, zero own panel slices (slot 1 = state(-1)) ----
  for (int i = tid; i < 24576; i += 1024) Wl0[i] = W0[q*24576 + i];
  for (int i = tid; i < 32768; i += 1024) Wl1[i] = W1[q*32768 + i];
  for (int i = tid; i < 12288; i += 1024) fcs[i] = FCW[i];
  for (int i = tid; i < 36*128; i += 1024) {
    int r = i >> 7, c = i & 127;
    embs[r*136 + c] = f2bf(emb[i]);
  }
  for (int i = tid; i < 4096; i += 1024) {
    int row = i >> 4, c = i & 15;
    int off = SLOT + (q>>1)*8192 + row*32 + (q&1)*16 + c;
    gh0[off] = 0; gh1[off] = 0;
  }
  if (tid < 16) {
    int row = g*256 + q*16 + tid;
    int cnt = 0;
    for (int s = 0; s < SLEN; s++) cnt += (x[(size_t)row*SLEN + s] != 0) ? 1 : 0;
    invlen_l[tid] = 1.0f / (float)cnt;
  }
  __syncthreads();
  if (tid == 0) {
    __threadfence();
    __hip_atomic_fetch_add(cc, 1u, __ATOMIC_RELEASE, __HIP_MEMORY_SCOPE_AGENT);
  }

  // hoisted invariants
  const int ch = 16*q + l15;
  const float bi0 = b0[ch], bf0 = b0[256+ch], bg0 = b0[512+ch], bo0 = b0[768+ch];
  const float bi1 = b1[ch], bf1 = b1[256+ch], bg1 = b1[512+ch], bo1 = b1[768+ch];
  const bool  v2  = (l15 < 4);
  const float lb0 = fcb[l15], lb1 = fcb[16 + l15];
  const float lb2 = v2 ? fcb[32 + l15] : 0.f;

  float c0s[2][4] = {};
  float c1s[2][4] = {};
  float mloss[4] = {0.f,0.f,0.f,0.f};

  for (int t = 0; t <= 128; t++) {
    // hoist x loads (never depend on panels)
    int tok0 = 0, tok1 = 0, tg4[4] = {0,0,0,0};
    if (w < 8 && t <= 126) {
      tok0 = x[(size_t)(g*256 + 32*w      + l15)*SLEN + t];
      tok1 = x[(size_t)(g*256 + 32*w + 16 + l15)*SLEN + t];
    }
    if (w == 7 && t >= 2) {
      #pragma unroll
      for (int j = 0; j < 4; j++)
        tg4[j] = x[(size_t)(g*256 + 16*q + 4*l4 + j)*SLEN + (t-1)];   // target of step t-2
    }

    // ---- single rendezvous: all 16 blocks of the group posted tick t-1 ----
    if (tid == 0) { spin_ge(cc, 16u*(t+1)); __threadfence(); }
    __syncthreads();

    if (w < 8) {
      // ================= L0: h0(t), rows 32w..32w+32, ch 16q..16q+16 =========
      if (t <= 126) {
        const short* hsrc = gh0 + ((t^1)&1)*SLOT;      // h0(t-1)
        f32x4 acc[2][4] = {};
        #pragma unroll
        for (int kt = 0; kt < 12; kt++) {
          bf16x8 Bf[4];
          #pragma unroll
          for (int G = 0; G < 4; G++)
            Bf[G] = *(const bf16x8*)(Wl0 + (G*12 + kt)*512 + lane*8);
          bf16x8 Af[2];
          if (kt < 4) {
            Af[0] = *(const bf16x8*)(embs + tok0*136 + kt*32 + l4*8);
            Af[1] = *(const bf16x8*)(embs + tok1*136 + kt*32 + l4*8);
          } else {
            Af[0] = *(const bf16x8*)(hsrc + (kt-4)*8192 + (32*w      + l15)*32 + l4*8);
            Af[1] = *(const bf16x8*)(hsrc + (kt-4)*8192 + (32*w + 16 + l15)*32 + l4*8);
          }
          #pragma unroll
          for (int m = 0; m < 2; m++)
            #pragma unroll
            for (int G = 0; G < 4; G++)
              acc[m][G] = __builtin_amdgcn_mfma_f32_16x16x32_bf16(Af[m], Bf[G], acc[m][G], 0, 0, 0);
        }
        short* hdst = gh0 + (t&1)*SLOT + (q>>1)*8192 + (q&1)*16 + l15;
        #pragma unroll
        for (int m = 0; m < 2; m++)
          #pragma unroll
          for (int j = 0; j < 4; j++) {
            float iv = fsig (acc[m][0][j] + bi0);
            float fv = fsig (acc[m][1][j] + bf0);
            float gv = ftanh(acc[m][2][j] + bg0);
            float ov = fsig (acc[m][3][j] + bo0);
            float c  = fv * c0s[m][j] + iv * gv;
            c0s[m][j] = c;
            hdst[(32*w + 16*m + 4*l4 + j)*32] = f2bf(ov * ftanh(c));
          }
      }
      // ================= FC + softmax + loss for step t-2 (wave 7) ===========
      if (w == 7 && t >= 2) {
        const short* h1c = gh1 + (t&1)*SLOT;           // h1(t-2)
        f32x4 a3[3] = {};
        #pragma unroll
        for (int kt = 0; kt < 8; kt++) {
          bf16x8 Ah = *(const bf16x8*)(h1c + kt*8192 + (16*q + l15)*32 + l4*8);
          #pragma unroll
          for (int n = 0; n < 3; n++) {
            bf16x8 Bf = *(const bf16x8*)(fcs + (n*8 + kt)*512 + lane*8);
            a3[n] = __builtin_amdgcn_mfma_f32_16x16x32_bf16(Ah, Bf, a3[n], 0, 0, 0);
          }
        }
        #pragma unroll
        for (int j = 0; j < 4; j++) {
          float g0 = fmaxf(a3[0][j] + lb0, 0.f);
          float g1 = fmaxf(a3[1][j] + lb1, 0.f);
          float g2 = v2 ? fmaxf(a3[2][j] + lb2, 0.f) : -INFINITY;
          float mx = fmaxf(fmaxf(g0, g1), g2);
          #pragma unroll
          for (int k = 1; k < 16; k <<= 1) mx = fmaxf(mx, __shfl_xor(mx, k, 64));
          float e0 = __expf(g0 - mx), e1 = __expf(g1 - mx);
          float e2 = v2 ? __expf(g2 - mx) : 0.f;
          float sm = e0 + e1 + e2;
          #pragma unroll
          for (int k = 1; k < 16; k <<= 1) sm += __shfl_xor(sm, k, 64);
          float inv = 1.0f / sm;
          int grow = g*256 + 16*q + 4*l4 + j;
          float* po = out + ((size_t)grow*TLEN + (t-2))*VOC;
          __builtin_nontemporal_store(e0 * inv, po + l15);
          __builtin_nontemporal_store(e1 * inv, po + 16 + l15);
          if (v2) __builtin_nontemporal_store(e2 * inv, po + 32 + l15);
          int tg = tg4[j];
          float sel = (tg < 16) ? g0 : ((tg < 32) ? g1 : g2);
          float ltg = __shfl(sel, (lane & 48) | (tg & 15), 64);
          float nll = mx + __logf(sm) - ltg;
          mloss[j] += (tg != 0) ? nll * invlen_l[4*l4 + j] : 0.f;
        }
      }
    } else {
      // ================= L1: h1(t-1), rows 32w8..+32, ch 16q..16q+16 =========
      if (t >= 1 && t <= 127) {
        const int w8 = w - 8;
        const int s  = t - 1;
        const short* h0src = gh0 + (s&1)*SLOT;         // h0(s)
        const short* h1src = gh1 + ((s^1)&1)*SLOT;     // h1(s-1)
        f32x4 acc[2][4] = {};
        #pragma unroll
        for (int kt = 0; kt < 16; kt++) {
          bf16x8 Bf[4];
          #pragma unroll
          for (int G = 0; G < 4; G++)
            Bf[G] = *(const bf16x8*)(Wl1 + (G*16 + kt)*512 + lane*8);
          bf16x8 Af[2];
          if (kt < 8) {
            Af[0] = *(const bf16x8*)(h0src + kt*8192 + (32*w8      + l15)*32 + l4*8);
            Af[1] = *(const bf16x8*)(h0src + kt*8192 + (32*w8 + 16 + l15)*32 + l4*8);
          } else {
            Af[0] = *(const bf16x8*)(h1src + (kt-8)*8192 + (32*w8      + l15)*32 + l4*8);
            Af[1] = *(const bf16x8*)(h1src + (kt-8)*8192 + (32*w8 + 16 + l15)*32 + l4*8);
          }
          #pragma unroll
          for (int m = 0; m < 2; m++)
            #pragma unroll
            for (int G = 0; G < 4; G++)
              acc[m][G] = __builtin_amdgcn_mfma_f32_16x16x32_bf16(Af[m], Bf[G], acc[m][G], 0, 0, 0);
        }
        short* hdst = gh1 + (s&1)*SLOT + (q>>1)*8192 + (q&1)*16 + l15;
        #pragma unroll
        for (int m = 0; m < 2; m++)
          #pragma unroll
          for (int j = 0; j < 4; j++) {
            float iv = fsig (acc[m][0][j] + bi1);
            float fv = fsig (acc[m][1][j] + bf1);
            float gv = ftanh(acc[m][2][j] + bg1);
            float ov = fsig (acc[m][3][j] + bo1);
            float c  = fv * c1s[m][j] + iv * gv;
            c1s[m][j] = c;
            hdst[(32*w8 + 16*m + 4*l4 + j)*32] = f2bf(ov * ftanh(c));
          }
      }
    }

    __syncthreads();                  // drains all waves' panel stores
    if (tid == 0 && t < 128) {
      __threadfence();
      __hip_atomic_fetch_add(cc, 1u, __ATOMIC_RELEASE, __HIP_MEMORY_SCOPE_AGENT);
    }
  } // tick loop

  if (w == 7 && l15 == 0) {
    float tot = 0.f;
    #pragma unroll
    for (int j = 0; j < 4; j++) {
      int grow = g*256 + 16*q + 4*l4 + j;
      __builtin_nontemporal_store(mloss[j], out + (size_t)MLOSS_OFF + grow);
      tot += mloss[j];
    }
    atomicAdd(out + LOSS_OFF, tot * (1.0f/4096.0f));
  }
}

// ===================== fallback (R2-style, ~9.6 ms) =====================
__global__ __launch_bounds__(1024, 4)
void lstm_small(const int* __restrict__ x, const float* __restrict__ emb,
                const float* __restrict__ fcb,
                const short* __restrict__ W0, const short* __restrict__ W1,
                const short* __restrict__ FCW,
                const float* __restrict__ b0, const float* __restrict__ b1,
                float* __restrict__ out)
{
  __shared__ __align__(16) short emb_s[36*136];
  __shared__ __align__(16) short h0_s[32*264];
  __shared__ __align__(16) short h1_s[32*264];
  __shared__ int   tok_s[32];
  __shared__ float invlen_s[32];

  const int tid  = threadIdx.x;
  const int lane = tid & 63;
  const int wv   = tid >> 6;
  const int l15  = lane & 15;
  const int l4   = lane >> 4;
  const int r0   = blockIdx.x * 32;

  for (int i = tid; i < 36*128; i += 1024) {
    int r = i >> 7, c = i & 127;
    emb_s[r*136 + c] = f2bf(emb[i]);
  }
  for (int i = tid; i < 32*264; i += 1024) { h0_s[i] = 0; h1_s[i] = 0; }
  if (tid < 32) {
    int cnt = 0;
    for (int s = 0; s < SLEN; s++) cnt += (x[(r0+tid)*SLEN + s] != 0) ? 1 : 0;
    invlen_s[tid] = 1.0f / (float)cnt;
    tok_s[tid] = x[(r0+tid)*SLEN + 0];
  }
  __syncthreads();

  const int ch = wv*16 + l15;
  const short* w0base = W0 + wv*24576 + lane*8;
  const short* w1base = W1 + wv*32768 + lane*8;
  const short* fcbase = FCW + lane*8;
  const float bi0 = b0[ch], bf0 = b0[256+ch], bg0 = b0[512+ch], bo0 = b0[768+ch];
  const float bi1 = b1[ch], bf1 = b1[256+ch], bg1 = b1[512+ch], bo1 = b1[768+ch];
  const bool  v2  = (l15 < 4);
  const float lb0 = fcb[l15], lb1 = fcb[16 + l15];
  const float lb2 = v2 ? fcb[32 + l15] : 0.f;

  float c0s[2][4] = {};
  float c1s[2][4] = {};
  float mloss[4] = {0.f,0.f,0.f,0.f};

  for (int t = 0; t < TLEN; t++) {
    int tokv[2];
    #pragma unroll
    for (int m = 0; m < 2; m++) tokv[m] = tok_s[m*16 + l15];
    float hn0[2][4];
    {
      f32x4 acc[2][4] = {};
      #pragma unroll
      for (int kt = 0; kt < 12; kt++) {
        bf16x8 Bf[4];
        #pragma unroll
        for (int G = 0; G < 4; G++) Bf[G] = *(const bf16x8*)(w0base + (G*12 + kt)*512);
        bf16x8 Af[2];
        #pragma unroll
        for (int m = 0; m < 2; m++) {
          if (kt < 4) Af[m] = *(const bf16x8*)(emb_s + tokv[m]*136 + kt*32 + l4*8);
          else        Af[m] = *(const bf16x8*)(h0_s + (m*16 + l15)*264 + (kt-4)*32 + l4*8);
        }
        #pragma unroll
        for (int m = 0; m < 2; m++)
          #pragma unroll
          for (int G = 0; G < 4; G++)
            acc[m][G] = __builtin_amdgcn_mfma_f32_16x16x32_bf16(Af[m], Bf[G], acc[m][G], 0, 0, 0);
      }
      #pragma unroll
      for (int m = 0; m < 2; m++)
        #pragma unroll
        for (int j = 0; j < 4; j++) {
          float iv = fsig (acc[m][0][j] + bi0);
          float fv = fsig (acc[m][1][j] + bf0);
          float gv = ftanh(acc[m][2][j] + bg0);
          float ov = fsig (acc[m][3][j] + bo0);
          float c  = fv * c0s[m][j] + iv * gv;
          c0s[m][j] = c;
          hn0[m][j] = ov * ftanh(c);
        }
    }
    __syncthreads();
    if (wv == 15 && lane < 32) tok_s[lane] = x[(r0+lane)*SLEN + t + 1];
    #pragma unroll
    for (int m = 0; m < 2; m++)
      #pragma unroll
      for (int j = 0; j < 4; j++)
        h0_s[(m*16 + l4*4 + j)*264 + ch] = f2bf(hn0[m][j]);
    __syncthreads();
    float hn1[2][4];
    {
      f32x4 acc[2][4] = {};
      #pragma unroll
      for (int kt = 0; kt < 16; kt++) {
        bf16x8 Bf[4];
        #pragma unroll
        for (int G = 0; G < 4; G++) Bf[G] = *(const bf16x8*)(w1base + (G*16 + kt)*512);
        bf16x8 Af[2];
        #pragma unroll
        for (int m = 0; m < 2; m++) {
          if (kt < 8) Af[m] = *(const bf16x8*)(h0_s + (m*16 + l15)*264 + kt*32 + l4*8);
          else        Af[m] = *(const bf16x8*)(h1_s + (m*16 + l15)*264 + (kt-8)*32 + l4*8);
        }
        #pragma unroll
        for (int m = 0; m < 2; m++)
          #pragma unroll
          for (int G = 0; G < 4; G++)
            acc[m][G] = __builtin_amdgcn_mfma_f32_16x16x32_bf16(Af[m], Bf[G], acc[m][G], 0, 0, 0);
      }
      #pragma unroll
      for (int m = 0; m < 2; m++)
        #pragma unroll
        for (int j = 0; j < 4; j++) {
          float iv = fsig (acc[m][0][j] + bi1);
          float fv = fsig (acc[m][1][j] + bf1);
          float gv = ftanh(acc[m][2][j] + bg1);
          float ov = fsig (acc[m][3][j] + bo1);
          float c  = fv * c1s[m][j] + iv * gv;
          c1s[m][j] = c;
          hn1[m][j] = ov * ftanh(c);
        }
    }
    __syncthreads();
    #pragma unroll
    for (int m = 0; m < 2; m++)
      #pragma unroll
      for (int j = 0; j < 4; j++)
        h1_s[(m*16 + l4*4 + j)*264 + ch] = f2bf(hn1[m][j]);
    __syncthreads();
    if (wv < 2) {
      const int wr = wv * 16;
      f32x4 a3[3] = {};
      #pragma unroll
      for (int kt = 0; kt < 8; kt++) {
        bf16x8 Ah = *(const bf16x8*)(h1_s + (wr + l15)*264 + kt*32 + l4*8);
        #pragma unroll
        for (int n = 0; n < 3; n++) {
          bf16x8 Bf = *(const bf16x8*)(fcbase + (n*8 + kt)*512);
          a3[n] = __builtin_amdgcn_mfma_f32_16x16x32_bf16(Ah, Bf, a3[n], 0, 0, 0);
        }
      }
      #pragma unroll
      for (int j = 0; j < 4; j++) {
        float g0 = fmaxf(a3[0][j] + lb0, 0.f);
        float g1 = fmaxf(a3[1][j] + lb1, 0.f);
        float g2 = v2 ? fmaxf(a3[2][j] + lb2, 0.f) : -INFINITY;
        float mx = fmaxf(fmaxf(g0, g1), g2);
        #pragma unroll
        for (int k = 1; k < 16; k <<= 1) mx = fmaxf(mx, __shfl_xor(mx, k, 64));
        float e0 = __expf(g0 - mx), e1 = __expf(g1 - mx);
        float e2 = v2 ? __expf(g2 - mx) : 0.f;
        float sm = e0 + e1 + e2;
        #pragma unroll
        for (int k = 1; k < 16; k <<= 1) sm += __shfl_xor(sm, k, 64);
        float inv = 1.0f / sm;
        int row = wr + l4*4 + j;
        float* po = out + ((size_t)(r0 + row)*TLEN + t)*VOC;
        __builtin_nontemporal_store(e0 * inv, po + l15);
        __builtin_nontemporal_store(e1 * inv, po + 16 + l15);
        if (v2) __builtin_nontemporal_store(e2 * inv, po + 32 + l15);
        int tg = tok_s[row];
        float sel = (tg < 16) ? g0 : ((tg < 32) ? g1 : g2);
        float ltg = __shfl(sel, (lane & 48) | (tg & 15), 64);
        float nll = mx + __logf(sm) - ltg;
        mloss[j] += (tg != 0) ? nll * invlen_s[row] : 0.f;
      }
    }
  }
  if (wv < 2 && l15 == 0) {
    float tot = 0.f;
    #pragma unroll
    for (int j = 0; j < 4; j++) {
      int row = wv*16 + l4*4 + j;
      __builtin_nontemporal_store(mloss[j], out + (size_t)MLOSS_OFF + r0 + row);
      tot += mloss[j];
    }
    atomicAdd(out + LOSS_OFF, tot * (1.0f/4096.0f));
  }
}

extern "C" void kernel_launch(void* const* d_in, const int* in_sizes, int n_in,
                              void* d_out, int out_size, void* d_ws, size_t ws_size,
                              hipStream_t stream) {
  const int*   x    = (const int*)  d_in[0];
  const float* emb  = (const float*)d_in[1];
  const float* Wih0 = (const float*)d_in[2];
  const float* Whh0 = (const float*)d_in[3];
  const float* bih0 = (const float*)d_in[4];
  const float* bhh0 = (const float*)d_in[5];
  const float* Wih1 = (const float*)d_in[6];
  const float* Whh1 = (const float*)d_in[7];
  const float* bih1 = (const float*)d_in[8];
  const float* bhh1 = (const float*)d_in[9];
  const float* fcW  = (const float*)d_in[10];
  const float* fcb  = (const float*)d_in[11];

  short* w0  = (short*)((char*)d_ws + WS_W0);
  short* w1  = (short*)((char*)d_ws + WS_W1);
  short* fcw = (short*)((char*)d_ws + WS_FC);
  float* b0  = (float*)((char*)d_ws + WS_B0);
  float* b1  = (float*)((char*)d_ws + WS_B1);
  float* out = (float*)d_out;

  bool big = (ws_size >= (size_t)WS_NEEDED);
  static int lds_ok = -1;
  if (big && lds_ok < 0) {
    hipError_t e = hipFuncSetAttribute((const void*)lstm_fuse,
                     hipFuncAttributeMaxDynamicSharedMemorySize, 149504);
    lds_ok = (e == hipSuccess) ? 1 : 0;
  }
  bool use_pipe = big && (lds_ok == 1);

  short*    h0bp = (short*)((char*)d_ws + WS_H0);
  short*    h1bp = (short*)((char*)d_ws + WS_H1);
  unsigned* ctr  = use_pipe ? (unsigned*)((char*)d_ws + WS_CTR) : nullptr;

  prep_kernel<<<3648, 256, 0, stream>>>(Wih0, Whh0, bih0, bhh0, Wih1, Whh1,
                                        bih1, bhh1, fcW, w0, w1, fcw, b0, b1, ctr, out);
  if (use_pipe) {
    lstm_fuse<<<256, 1024, 149504, stream>>>(x, emb, fcb, w0, w1, fcw, b0, b1,
                                             h0bp, h1bp, ctr, out);
  } else {
    lstm_small<<<128, 1024, 0, stream>>>(x, emb, fcb, w0, w1, fcw, b0, b1, out);
  }
}

// Round 6
// 3538.520 us; speedup vs baseline: 3.6730x; 1.0528x over previous
//
#include <hip/hip_runtime.h>

typedef float f32x4 __attribute__((ext_vector_type(4)));
typedef short bf16x8 __attribute__((ext_vector_type(8)));

#define SLEN 128
#define TLEN 127
#define VOC 36
#define NPROBS (4096*127*36)
#define MLOSS_OFF NPROBS
#define LOSS_OFF (NPROBS + 4096)

// packed weights (shorts): W0p[q16][G4][kt12][512], W1p[q16][G4][kt16][512], FCp[n3][kt8][512]
#define WS_W0 0
#define WS_W1 786432
#define WS_FC 1835008
#define WS_B0 1859584
#define WS_B1 1863680
#define NW0 393216
#define NW1 524288
#define NFC 12288

// pipeline buffers
#define WS_H0  2097152              // short[16 grp][2 slot][8 ktile][256 row][32 ch] = 4 MB
#define WS_H1  6291456              // same
#define WS_CTR 10485760             // flags: 16 grp x 16 blk x 128B line = 32 KB
#define WS_NEEDED 10518528

#define GRP 131072                  // shorts per group (2 slots)
#define SLOT 65536                  // shorts per slot

__device__ __forceinline__ short f2bf(float f){
  unsigned u = __float_as_uint(f);
  u += 0x7fffu + ((u >> 16) & 1u);
  return (short)(u >> 16);
}
__device__ __forceinline__ float fsig(float x){ return 1.0f/(1.0f + __expf(-x)); }
__device__ __forceinline__ float ftanh(float x){ return 1.0f - 2.0f/(1.0f + __expf(2.0f*x)); }

__global__ void prep_kernel(const float* __restrict__ Wih0, const float* __restrict__ Whh0,
                            const float* __restrict__ bih0, const float* __restrict__ bhh0,
                            const float* __restrict__ Wih1, const float* __restrict__ Whh1,
                            const float* __restrict__ bih1, const float* __restrict__ bhh1,
                            const float* __restrict__ fcW,
                            short* __restrict__ w0, short* __restrict__ w1, short* __restrict__ fcw,
                            float* __restrict__ b0, float* __restrict__ b1,
                            unsigned* __restrict__ ctr,
                            float* __restrict__ out)
{
  int idx = blockIdx.x*256 + threadIdx.x;
  if (idx == 0) out[LOSS_OFF] = 0.0f;
  if (idx < NW0) {
    int wv = idx / 24576;
    int r1 = idx - wv*24576;
    int G  = r1 / 6144;
    int r2 = r1 - G*6144;
    int kt = r2 / 512;
    int r3 = r2 - kt*512;
    int ln = r3 >> 3, e = r3 & 7;
    int row = G*256 + wv*16 + (ln & 15);
    int col = kt*32 + (ln>>4)*8 + e;
    float v = (col < 128) ? Wih0[row*128 + col] : Whh0[row*256 + (col-128)];
    w0[idx] = f2bf(v);
  } else if (idx < NW0 + NW1) {
    int i2 = idx - NW0;
    int wv = i2 / 32768;
    int r1 = i2 - wv*32768;
    int G  = r1 / 8192;
    int r2 = r1 - G*8192;
    int kt = r2 / 512;
    int r3 = r2 - kt*512;
    int ln = r3 >> 3, e = r3 & 7;
    int row = G*256 + wv*16 + (ln & 15);
    int col = kt*32 + (ln>>4)*8 + e;
    float v = (col < 256) ? Wih1[row*256 + col] : Whh1[row*256 + (col-256)];
    w1[i2] = f2bf(v);
  } else if (idx < NW0 + NW1 + NFC) {
    int i2 = idx - (NW0 + NW1);
    int n  = i2 / 4096;
    int r1 = i2 - n*4096;
    int kt = r1 / 512;
    int r3 = r1 - kt*512;
    int ln = r3 >> 3, e = r3 & 7;
    int row = n*16 + (ln & 15);
    int col = kt*32 + (ln>>4)*8 + e;
    fcw[i2] = (row < VOC) ? f2bf(fcW[row*256 + col]) : (short)0;
  } else if (idx < NW0 + NW1 + NFC + 1024) {
    int i2 = idx - (NW0 + NW1 + NFC);
    b0[i2] = bih0[i2] + bhh0[i2];
  } else if (idx < NW0 + NW1 + NFC + 2048) {
    int i2 = idx - (NW0 + NW1 + NFC + 1024);
    b1[i2] = bih1[i2] + bhh1[i2];
  } else if (ctr && idx < NW0 + NW1 + NFC + 2048 + 8192) {
    ctr[idx - (NW0 + NW1 + NFC + 2048)] = 0u;
  }
}

// ============ merged-role persistent kernel: 1 flag-rendezvous per tick ============
// 256 blocks, 1/CU. g = (b&7)+8*(b>>7), q = (b>>3)&15.
// Block q holds channels [16q,16q+16) of BOTH layers.
// Tick t: waves 0-7 -> h0(t); waves 8-15 -> h1(t-1); wave 7 also FC(t-2).
__global__ __launch_bounds__(1024, 4)
void lstm_fuse(const int* __restrict__ x, const float* __restrict__ emb,
               const float* __restrict__ fcb,
               const short* __restrict__ W0, const short* __restrict__ W1,
               const short* __restrict__ FCW,
               const float* __restrict__ b0, const float* __restrict__ b1,
               short* __restrict__ h0b, short* __restrict__ h1b,
               unsigned* __restrict__ flags,
               float* __restrict__ out)
{
  extern __shared__ short lds[];
  short* Wl0  = lds;            // 24576 shorts (48 KB)
  short* Wl1  = lds + 24576;    // 32768 shorts (64 KB)
  short* fcs  = lds + 57344;    // 12288 shorts (24 KB)
  short* embs = lds + 69632;    // 36*136 = 4896 shorts
  float* invlen_l = (float*)(lds + 74528); // 16 floats

  const int tid  = threadIdx.x;
  const int lane = tid & 63;
  const int w    = tid >> 6;      // 0..15
  const int l15  = lane & 15;
  const int l4   = lane >> 4;

  const int b = blockIdx.x;
  const int g = (b & 7) + 8*(b >> 7);
  const int q = (b >> 3) & 15;

  unsigned* grp_flags = flags + g*512;          // 16 lines x 32 uints
  unsigned* my_flag   = grp_flags + q*32;
  short* gh0 = h0b + g*GRP;
  short* gh1 = h1b + g*GRP;

  // ---- prologue: stage LDS, zero own panel slices (slot 1 = state(-1)) ----
  for (int i = tid; i < 24576; i += 1024) Wl0[i] = W0[q*24576 + i];
  for (int i = tid; i < 32768; i += 1024) Wl1[i] = W1[q*32768 + i];
  for (int i = tid; i < 12288; i += 1024) fcs[i] = FCW[i];
  for (int i = tid; i < 36*128; i += 1024) {
    int r = i >> 7, c = i & 127;
    embs[r*136 + c] = f2bf(emb[i]);
  }
  for (int i = tid; i < 4096; i += 1024) {
    int row = i >> 4, c = i & 15;
    int off = SLOT + (q>>1)*8192 + row*32 + (q&1)*16 + c;
    gh0[off] = 0; gh1[off] = 0;
  }
  if (tid < 16) {
    int row = g*256 + q*16 + tid;
    int cnt = 0;
    for (int s = 0; s < SLEN; s++) cnt += (x[(size_t)row*SLEN + s] != 0) ? 1 : 0;
    invlen_l[tid] = 1.0f / (float)cnt;
  }
  __syncthreads();
  if (tid == 0) {
    __threadfence();
    __hip_atomic_store(my_flag, 1u, __ATOMIC_RELEASE, __HIP_MEMORY_SCOPE_AGENT);
  }

  // hoisted invariants
  const int ch = 16*q + l15;
  const float bi0 = b0[ch], bf0 = b0[256+ch], bg0 = b0[512+ch], bo0 = b0[768+ch];
  const float bi1 = b1[ch], bf1 = b1[256+ch], bg1 = b1[512+ch], bo1 = b1[768+ch];
  const bool  v2  = (l15 < 4);
  const float lb0 = fcb[l15], lb1 = fcb[16 + l15];
  const float lb2 = v2 ? fcb[32 + l15] : 0.f;

  float c0s[2][4] = {};
  float c1s[2][4] = {};
  float mloss[4] = {0.f,0.f,0.f,0.f};

  for (int t = 0; t <= 128; t++) {
    // hoist x loads (never depend on panels)
    int tok0 = 0, tok1 = 0, tg4[4] = {0,0,0,0};
    if (w < 8 && t <= 126) {
      tok0 = x[(size_t)(g*256 + 32*w      + l15)*SLEN + t];
      tok1 = x[(size_t)(g*256 + 32*w + 16 + l15)*SLEN + t];
    }
    if (w == 7 && t >= 2) {
      #pragma unroll
      for (int j = 0; j < 4; j++)
        tg4[j] = x[(size_t)(g*256 + 16*q + 4*l4 + j)*SLEN + (t-1)];   // target of step t-2
    }

    // ---- flag rendezvous: lane i polls sibling i's own-line flag ----
    if (tid < 16) {
      const unsigned* fp = grp_flags + tid*32;
      while (__hip_atomic_load(fp, __ATOMIC_ACQUIRE, __HIP_MEMORY_SCOPE_AGENT) < (unsigned)(t+1))
        __builtin_amdgcn_s_sleep(1);
    }
    if (tid == 0) __threadfence();
    __syncthreads();

    if (w < 8) {
      // ================= L0: h0(t), rows 32w..32w+32, ch 16q..16q+16 =========
      if (t <= 126) {
        const short* hsrc = gh0 + ((t^1)&1)*SLOT;      // h0(t-1)
        f32x4 acc[2][4] = {};
        #pragma unroll
        for (int kt = 0; kt < 12; kt++) {
          bf16x8 Bf[4];
          #pragma unroll
          for (int G = 0; G < 4; G++)
            Bf[G] = *(const bf16x8*)(Wl0 + (G*12 + kt)*512 + lane*8);
          bf16x8 Af[2];
          if (kt < 4) {
            Af[0] = *(const bf16x8*)(embs + tok0*136 + kt*32 + l4*8);
            Af[1] = *(const bf16x8*)(embs + tok1*136 + kt*32 + l4*8);
          } else {
            Af[0] = *(const bf16x8*)(hsrc + (kt-4)*8192 + (32*w      + l15)*32 + l4*8);
            Af[1] = *(const bf16x8*)(hsrc + (kt-4)*8192 + (32*w + 16 + l15)*32 + l4*8);
          }
          #pragma unroll
          for (int m = 0; m < 2; m++)
            #pragma unroll
            for (int G = 0; G < 4; G++)
              acc[m][G] = __builtin_amdgcn_mfma_f32_16x16x32_bf16(Af[m], Bf[G], acc[m][G], 0, 0, 0);
        }
        short* hdst = gh0 + (t&1)*SLOT + (q>>1)*8192 + (q&1)*16 + l15;
        #pragma unroll
        for (int m = 0; m < 2; m++)
          #pragma unroll
          for (int j = 0; j < 4; j++) {
            float iv = fsig (acc[m][0][j] + bi0);
            float fv = fsig (acc[m][1][j] + bf0);
            float gv = ftanh(acc[m][2][j] + bg0);
            float ov = fsig (acc[m][3][j] + bo0);
            float c  = fv * c0s[m][j] + iv * gv;
            c0s[m][j] = c;
            hdst[(32*w + 16*m + 4*l4 + j)*32] = f2bf(ov * ftanh(c));
          }
      }
      // ================= FC + softmax + loss for step t-2 (wave 7) ===========
      if (w == 7 && t >= 2) {
        const short* h1c = gh1 + (t&1)*SLOT;           // h1(t-2)
        f32x4 a3[3] = {};
        #pragma unroll
        for (int kt = 0; kt < 8; kt++) {
          bf16x8 Ah = *(const bf16x8*)(h1c + kt*8192 + (16*q + l15)*32 + l4*8);
          #pragma unroll
          for (int n = 0; n < 3; n++) {
            bf16x8 Bf = *(const bf16x8*)(fcs + (n*8 + kt)*512 + lane*8);
            a3[n] = __builtin_amdgcn_mfma_f32_16x16x32_bf16(Ah, Bf, a3[n], 0, 0, 0);
          }
        }
        #pragma unroll
        for (int j = 0; j < 4; j++) {
          float g0 = fmaxf(a3[0][j] + lb0, 0.f);
          float g1 = fmaxf(a3[1][j] + lb1, 0.f);
          float g2 = v2 ? fmaxf(a3[2][j] + lb2, 0.f) : -INFINITY;
          float mx = fmaxf(fmaxf(g0, g1), g2);
          #pragma unroll
          for (int k = 1; k < 16; k <<= 1) mx = fmaxf(mx, __shfl_xor(mx, k, 64));
          float e0 = __expf(g0 - mx), e1 = __expf(g1 - mx);
          float e2 = v2 ? __expf(g2 - mx) : 0.f;
          float sm = e0 + e1 + e2;
          #pragma unroll
          for (int k = 1; k < 16; k <<= 1) sm += __shfl_xor(sm, k, 64);
          float inv = 1.0f / sm;
          int grow = g*256 + 16*q + 4*l4 + j;
          float* po = out + ((size_t)grow*TLEN + (t-2))*VOC;
          __builtin_nontemporal_store(e0 * inv, po + l15);
          __builtin_nontemporal_store(e1 * inv, po + 16 + l15);
          if (v2) __builtin_nontemporal_store(e2 * inv, po + 32 + l15);
          int tg = tg4[j];
          float sel = (tg < 16) ? g0 : ((tg < 32) ? g1 : g2);
          float ltg = __shfl(sel, (lane & 48) | (tg & 15), 64);
          float nll = mx + __logf(sm) - ltg;
          mloss[j] += (tg != 0) ? nll * invlen_l[4*l4 + j] : 0.f;
        }
      }
    } else {
      // ================= L1: h1(t-1), rows 32w8..+32, ch 16q..16q+16 =========
      if (t >= 1 && t <= 127) {
        const int w8 = w - 8;
        const int s  = t - 1;
        const short* h0src = gh0 + (s&1)*SLOT;         // h0(s)
        const short* h1src = gh1 + ((s^1)&1)*SLOT;     // h1(s-1)
        f32x4 acc[2][4] = {};
        #pragma unroll
        for (int kt = 0; kt < 16; kt++) {
          bf16x8 Bf[4];
          #pragma unroll
          for (int G = 0; G < 4; G++)
            Bf[G] = *(const bf16x8*)(Wl1 + (G*16 + kt)*512 + lane*8);
          bf16x8 Af[2];
          if (kt < 8) {
            Af[0] = *(const bf16x8*)(h0src + kt*8192 + (32*w8      + l15)*32 + l4*8);
            Af[1] = *(const bf16x8*)(h0src + kt*8192 + (32*w8 + 16 + l15)*32 + l4*8);
          } else {
            Af[0] = *(const bf16x8*)(h1src + (kt-8)*8192 + (32*w8      + l15)*32 + l4*8);
            Af[1] = *(const bf16x8*)(h1src + (kt-8)*8192 + (32*w8 + 16 + l15)*32 + l4*8);
          }
          #pragma unroll
          for (int m = 0; m < 2; m++)
            #pragma unroll
            for (int G = 0; G < 4; G++)
              acc[m][G] = __builtin_amdgcn_mfma_f32_16x16x32_bf16(Af[m], Bf[G], acc[m][G], 0, 0, 0);
        }
        short* hdst = gh1 + (s&1)*SLOT + (q>>1)*8192 + (q&1)*16 + l15;
        #pragma unroll
        for (int m = 0; m < 2; m++)
          #pragma unroll
          for (int j = 0; j < 4; j++) {
            float iv = fsig (acc[m][0][j] + bi1);
            float fv = fsig (acc[m][1][j] + bf1);
            float gv = ftanh(acc[m][2][j] + bg1);
            float ov = fsig (acc[m][3][j] + bo1);
            float c  = fv * c1s[m][j] + iv * gv;
            c1s[m][j] = c;
            hdst[(32*w8 + 16*m + 4*l4 + j)*32] = f2bf(ov * ftanh(c));
          }
      }
    }

    __syncthreads();                  // drains all waves' panel stores/loads
    if (tid == 0 && t < 128) {
      __threadfence();
      __hip_atomic_store(my_flag, (unsigned)(t+2), __ATOMIC_RELEASE, __HIP_MEMORY_SCOPE_AGENT);
    }
  } // tick loop

  if (w == 7 && l15 == 0) {
    float tot = 0.f;
    #pragma unroll
    for (int j = 0; j < 4; j++) {
      int grow = g*256 + 16*q + 4*l4 + j;
      __builtin_nontemporal_store(mloss[j], out + (size_t)MLOSS_OFF + grow);
      tot += mloss[j];
    }
    atomicAdd(out + LOSS_OFF, tot * (1.0f/4096.0f));
  }
}

// ===================== fallback (R2-style, ~9.6 ms) =====================
__global__ __launch_bounds__(1024, 4)
void lstm_small(const int* __restrict__ x, const float* __restrict__ emb,
                const float* __restrict__ fcb,
                const short* __restrict__ W0, const short* __restrict__ W1,
                const short* __restrict__ FCW,
                const float* __restrict__ b0, const float* __restrict__ b1,
                float* __restrict__ out)
{
  __shared__ __align__(16) short emb_s[36*136];
  __shared__ __align__(16) short h0_s[32*264];
  __shared__ __align__(16) short h1_s[32*264];
  __shared__ int   tok_s[32];
  __shared__ float invlen_s[32];

  const int tid  = threadIdx.x;
  const int lane = tid & 63;
  const int wv   = tid >> 6;
  const int l15  = lane & 15;
  const int l4   = lane >> 4;
  const int r0   = blockIdx.x * 32;

  for (int i = tid; i < 36*128; i += 1024) {
    int r = i >> 7, c = i & 127;
    emb_s[r*136 + c] = f2bf(emb[i]);
  }
  for (int i = tid; i < 32*264; i += 1024) { h0_s[i] = 0; h1_s[i] = 0; }
  if (tid < 32) {
    int cnt = 0;
    for (int s = 0; s < SLEN; s++) cnt += (x[(r0+tid)*SLEN + s] != 0) ? 1 : 0;
    invlen_s[tid] = 1.0f / (float)cnt;
    tok_s[tid] = x[(r0+tid)*SLEN + 0];
  }
  __syncthreads();

  const int ch = wv*16 + l15;
  const short* w0base = W0 + wv*24576 + lane*8;
  const short* w1base = W1 + wv*32768 + lane*8;
  const short* fcbase = FCW + lane*8;
  const float bi0 = b0[ch], bf0 = b0[256+ch], bg0 = b0[512+ch], bo0 = b0[768+ch];
  const float bi1 = b1[ch], bf1 = b1[256+ch], bg1 = b1[512+ch], bo1 = b1[768+ch];
  const bool  v2  = (l15 < 4);
  const float lb0 = fcb[l15], lb1 = fcb[16 + l15];
  const float lb2 = v2 ? fcb[32 + l15] : 0.f;

  float c0s[2][4] = {};
  float c1s[2][4] = {};
  float mloss[4] = {0.f,0.f,0.f,0.f};

  for (int t = 0; t < TLEN; t++) {
    int tokv[2];
    #pragma unroll
    for (int m = 0; m < 2; m++) tokv[m] = tok_s[m*16 + l15];
    float hn0[2][4];
    {
      f32x4 acc[2][4] = {};
      #pragma unroll
      for (int kt = 0; kt < 12; kt++) {
        bf16x8 Bf[4];
        #pragma unroll
        for (int G = 0; G < 4; G++) Bf[G] = *(const bf16x8*)(w0base + (G*12 + kt)*512);
        bf16x8 Af[2];
        #pragma unroll
        for (int m = 0; m < 2; m++) {
          if (kt < 4) Af[m] = *(const bf16x8*)(emb_s + tokv[m]*136 + kt*32 + l4*8);
          else        Af[m] = *(const bf16x8*)(h0_s + (m*16 + l15)*264 + (kt-4)*32 + l4*8);
        }
        #pragma unroll
        for (int m = 0; m < 2; m++)
          #pragma unroll
          for (int G = 0; G < 4; G++)
            acc[m][G] = __builtin_amdgcn_mfma_f32_16x16x32_bf16(Af[m], Bf[G], acc[m][G], 0, 0, 0);
      }
      #pragma unroll
      for (int m = 0; m < 2; m++)
        #pragma unroll
        for (int j = 0; j < 4; j++) {
          float iv = fsig (acc[m][0][j] + bi0);
          float fv = fsig (acc[m][1][j] + bf0);
          float gv = ftanh(acc[m][2][j] + bg0);
          float ov = fsig (acc[m][3][j] + bo0);
          float c  = fv * c0s[m][j] + iv * gv;
          c0s[m][j] = c;
          hn0[m][j] = ov * ftanh(c);
        }
    }
    __syncthreads();
    if (wv == 15 && lane < 32) tok_s[lane] = x[(r0+lane)*SLEN + t + 1];
    #pragma unroll
    for (int m = 0; m < 2; m++)
      #pragma unroll
      for (int j = 0; j < 4; j++)
        h0_s[(m*16 + l4*4 + j)*264 + ch] = f2bf(hn0[m][j]);
    __syncthreads();
    float hn1[2][4];
    {
      f32x4 acc[2][4] = {};
      #pragma unroll
      for (int kt = 0; kt < 16; kt++) {
        bf16x8 Bf[4];
        #pragma unroll
        for (int G = 0; G < 4; G++) Bf[G] = *(const bf16x8*)(w1base + (G*16 + kt)*512);
        bf16x8 Af[2];
        #pragma unroll
        for (int m = 0; m < 2; m++) {
          if (kt < 8) Af[m] = *(const bf16x8*)(h0_s + (m*16 + l15)*264 + kt*32 + l4*8);
          else        Af[m] = *(const bf16x8*)(h1_s + (m*16 + l15)*264 + (kt-8)*32 + l4*8);
        }
        #pragma unroll
        for (int m = 0; m < 2; m++)
          #pragma unroll
          for (int G = 0; G < 4; G++)
            acc[m][G] = __builtin_amdgcn_mfma_f32_16x16x32_bf16(Af[m], Bf[G], acc[m][G], 0, 0, 0);
      }
      #pragma unroll
      for (int m = 0; m < 2; m++)
        #pragma unroll
        for (int j = 0; j < 4; j++) {
          float iv = fsig (acc[m][0][j] + bi1);
          float fv = fsig (acc[m][1][j] + bf1);
          float gv = ftanh(acc[m][2][j] + bg1);
          float ov = fsig (acc[m][3][j] + bo1);
          float c  = fv * c1s[m][j] + iv * gv;
          c1s[m][j] = c;
          hn1[m][j] = ov * ftanh(c);
        }
    }
    __syncthreads();
    #pragma unroll
    for (int m = 0; m < 2; m++)
      #pragma unroll
      for (int j = 0; j < 4; j++)
        h1_s[(m*16 + l4*4 + j)*264 + ch] = f2bf(hn1[m][j]);
    __syncthreads();
    if (wv < 2) {
      const int wr = wv * 16;
      f32x4 a3[3] = {};
      #pragma unroll
      for (int kt = 0; kt < 8; kt++) {
        bf16x8 Ah = *(const bf16x8*)(h1_s + (wr + l15)*264 + kt*32 + l4*8);
        #pragma unroll
        for (int n = 0; n < 3; n++) {
          bf16x8 Bf = *(const bf16x8*)(fcbase + (n*8 + kt)*512);
          a3[n] = __builtin_amdgcn_mfma_f32_16x16x32_bf16(Ah, Bf, a3[n], 0, 0, 0);
        }
      }
      #pragma unroll
      for (int j = 0; j < 4; j++) {
        float g0 = fmaxf(a3[0][j] + lb0, 0.f);
        float g1 = fmaxf(a3[1][j] + lb1, 0.f);
        float g2 = v2 ? fmaxf(a3[2][j] + lb2, 0.f) : -INFINITY;
        float mx = fmaxf(fmaxf(g0, g1), g2);
        #pragma unroll
        for (int k = 1; k < 16; k <<= 1) mx = fmaxf(mx, __shfl_xor(mx, k, 64));
        float e0 = __expf(g0 - mx), e1 = __expf(g1 - mx);
        float e2 = v2 ? __expf(g2 - mx) : 0.f;
        float sm = e0 + e1 + e2;
        #pragma unroll
        for (int k = 1; k < 16; k <<= 1) sm += __shfl_xor(sm, k, 64);
        float inv = 1.0f / sm;
        int row = wr + l4*4 + j;
        float* po = out + ((size_t)(r0 + row)*TLEN + t)*VOC;
        __builtin_nontemporal_store(e0 * inv, po + l15);
        __builtin_nontemporal_store(e1 * inv, po + 16 + l15);
        if (v2) __builtin_nontemporal_store(e2 * inv, po + 32 + l15);
        int tg = tok_s[row];
        float sel = (tg < 16) ? g0 : ((tg < 32) ? g1 : g2);
        float ltg = __shfl(sel, (lane & 48) | (tg & 15), 64);
        float nll = mx + __logf(sm) - ltg;
        mloss[j] += (tg != 0) ? nll * invlen_s[row] : 0.f;
      }
    }
  }
  if (wv < 2 && l15 == 0) {
    float tot = 0.f;
    #pragma unroll
    for (int j = 0; j < 4; j++) {
      int row = wv*16 + l4*4 + j;
      __builtin_nontemporal_store(mloss[j], out + (size_t)MLOSS_OFF + r0 + row);
      tot += mloss[j];
    }
    atomicAdd(out + LOSS_OFF, tot * (1.0f/4096.0f));
  }
}

extern "C" void kernel_launch(void* const* d_in, const int* in_sizes, int n_in,
                              void* d_out, int out_size, void* d_ws, size_t ws_size,
                              hipStream_t stream) {
  const int*   x    = (const int*)  d_in[0];
  const float* emb  = (const float*)d_in[1];
  const float* Wih0 = (const float*)d_in[2];
  const float* Whh0 = (const float*)d_in[3];
  const float* bih0 = (const float*)d_in[4];
  const float* bhh0 = (const float*)d_in[5];
  const float* Wih1 = (const float*)d_in[6];
  const float* Whh1 = (const float*)d_in[7];
  const float* bih1 = (const float*)d_in[8];
  const float* bhh1 = (const float*)d_in[9];
  const float* fcW  = (const float*)d_in[10];
  const float* fcb  = (const float*)d_in[11];

  short* w0  = (short*)((char*)d_ws + WS_W0);
  short* w1  = (short*)((char*)d_ws + WS_W1);
  short* fcw = (short*)((char*)d_ws + WS_FC);
  float* b0  = (float*)((char*)d_ws + WS_B0);
  float* b1  = (float*)((char*)d_ws + WS_B1);
  float* out = (float*)d_out;

  bool big = (ws_size >= (size_t)WS_NEEDED);
  static int lds_ok = -1;
  if (big && lds_ok < 0) {
    hipError_t e = hipFuncSetAttribute((const void*)lstm_fuse,
                     hipFuncAttributeMaxDynamicSharedMemorySize, 149504);
    lds_ok = (e == hipSuccess) ? 1 : 0;
  }
  bool use_pipe = big && (lds_ok == 1);

  short*    h0bp = (short*)((char*)d_ws + WS_H0);
  short*    h1bp = (short*)((char*)d_ws + WS_H1);
  unsigned* ctr  = use_pipe ? (unsigned*)((char*)d_ws + WS_CTR) : nullptr;

  prep_kernel<<<3672, 256, 0, stream>>>(Wih0, Whh0, bih0, bhh0, Wih1, Whh1,
                                        bih1, bhh1, fcW, w0, w1, fcw, b0, b1, ctr, out);
  if (use_pipe) {
    lstm_fuse<<<256, 1024, 149504, stream>>>(x, emb, fcb, w0, w1, fcw, b0, b1,
                                             h0bp, h1bp, ctr, out);
  } else {
    lstm_small<<<128, 1024, 0, stream>>>(x, emb, fcb, w0, w1, fcw, b0, b1, out);
  }
}

// Round 7
// 1798.255 us; speedup vs baseline: 7.2276x; 1.9678x over previous
//
#include <hip/hip_runtime.h>

typedef float f32x4 __attribute__((ext_vector_type(4)));
typedef short bf16x8 __attribute__((ext_vector_type(8)));

#define SLEN 128
#define TLEN 127
#define VOC 36
#define NPROBS (4096*127*36)
#define MLOSS_OFF NPROBS
#define LOSS_OFF (NPROBS + 4096)

// packed weights (shorts): W0p[q16][G4][kt12][512], W1p[q16][G4][kt16][512], FCp[n3][kt8][512]
#define WS_W0 0
#define WS_W1 786432
#define WS_FC 1835008
#define WS_B0 1859584
#define WS_B1 1863680
#define NW0 393216
#define NW1 524288
#define NFC 12288

// pipeline buffers
#define WS_H0  2097152              // short[16 grp][2 slot][8 ktile][256 row][32 ch] = 4 MB
#define WS_H1  6291456              // same
#define WS_CTR 10485760             // flags: 16 grp x 16 blk x 128B line = 32 KB
#define WS_NEEDED 10518528

#define GRP 131072                  // shorts per group (2 slots)
#define SLOT 65536                  // shorts per slot

__device__ __forceinline__ short f2bf(float f){
  unsigned u = __float_as_uint(f);
  u += 0x7fffu + ((u >> 16) & 1u);
  return (short)(u >> 16);
}
__device__ __forceinline__ float fsig(float x){ return 1.0f/(1.0f + __expf(-x)); }
__device__ __forceinline__ float ftanh(float x){ return 1.0f - 2.0f/(1.0f + __expf(2.0f*x)); }

// ---- fine-grained coherent (MALL) accessors: no cache-maintenance ops ----
__device__ __forceinline__ void ld16_sc(bf16x8* d, const short* p){
  asm volatile("global_load_dwordx4 %0, %1, off sc0 sc1" : "=&v"(*d) : "v"(p));
}
__device__ __forceinline__ void st2_sc(short* p, short v){
  asm volatile("global_store_short %0, %1, off sc0 sc1" :: "v"(p), "v"(v));
}
__device__ __forceinline__ void vmdrain_sb(){
  asm volatile("s_waitcnt vmcnt(0)" ::: "memory");
  __builtin_amdgcn_sched_barrier(0);
}
__device__ __forceinline__ unsigned ldflag_sc(const unsigned* p){
  unsigned r;
  asm volatile("global_load_dword %0, %1, off sc0 sc1\n\ts_waitcnt vmcnt(0)"
               : "=&v"(r) : "v"(p) : "memory");
  return r;
}
__device__ __forceinline__ void stflag_sc(unsigned* p, unsigned v){
  asm volatile("global_store_dword %0, %1, off sc0 sc1" :: "v"(p), "v"(v) : "memory");
}

__global__ void prep_kernel(const float* __restrict__ Wih0, const float* __restrict__ Whh0,
                            const float* __restrict__ bih0, const float* __restrict__ bhh0,
                            const float* __restrict__ Wih1, const float* __restrict__ Whh1,
                            const float* __restrict__ bih1, const float* __restrict__ bhh1,
                            const float* __restrict__ fcW,
                            short* __restrict__ w0, short* __restrict__ w1, short* __restrict__ fcw,
                            float* __restrict__ b0, float* __restrict__ b1,
                            float* __restrict__ out)
{
  int idx = blockIdx.x*256 + threadIdx.x;
  if (idx == 0) out[LOSS_OFF] = 0.0f;
  if (idx < NW0) {
    int wv = idx / 24576;
    int r1 = idx - wv*24576;
    int G  = r1 / 6144;
    int r2 = r1 - G*6144;
    int kt = r2 / 512;
    int r3 = r2 - kt*512;
    int ln = r3 >> 3, e = r3 & 7;
    int row = G*256 + wv*16 + (ln & 15);
    int col = kt*32 + (ln>>4)*8 + e;
    float v = (col < 128) ? Wih0[row*128 + col] : Whh0[row*256 + (col-128)];
    w0[idx] = f2bf(v);
  } else if (idx < NW0 + NW1) {
    int i2 = idx - NW0;
    int wv = i2 / 32768;
    int r1 = i2 - wv*32768;
    int G  = r1 / 8192;
    int r2 = r1 - G*8192;
    int kt = r2 / 512;
    int r3 = r2 - kt*512;
    int ln = r3 >> 3, e = r3 & 7;
    int row = G*256 + wv*16 + (ln & 15);
    int col = kt*32 + (ln>>4)*8 + e;
    float v = (col < 256) ? Wih1[row*256 + col] : Whh1[row*256 + (col-256)];
    w1[i2] = f2bf(v);
  } else if (idx < NW0 + NW1 + NFC) {
    int i2 = idx - (NW0 + NW1);
    int n  = i2 / 4096;
    int r1 = i2 - n*4096;
    int kt = r1 / 512;
    int r3 = r1 - kt*512;
    int ln = r3 >> 3, e = r3 & 7;
    int row = n*16 + (ln & 15);
    int col = kt*32 + (ln>>4)*8 + e;
    fcw[i2] = (row < VOC) ? f2bf(fcW[row*256 + col]) : (short)0;
  } else if (idx < NW0 + NW1 + NFC + 1024) {
    int i2 = idx - (NW0 + NW1 + NFC);
    b0[i2] = bih0[i2] + bhh0[i2];
  } else if (idx < NW0 + NW1 + NFC + 2048) {
    int i2 = idx - (NW0 + NW1 + NFC + 1024);
    b1[i2] = bih1[i2] + bhh1[i2];
  }
}

// ============ merged-role persistent kernel, sc0sc1 fence-free fabric ============
// 256 blocks, 1/CU. g = (b&7)+8*(b>>7), q = (b>>3)&15.
// Block q holds channels [16q,16q+16) of BOTH layers.
// Tick t: waves 0-7 -> h0(t); waves 8-15 -> h1(t-1); wave 7 also FC(t-2).
__global__ __launch_bounds__(1024, 4)
void lstm_fuse(const int* __restrict__ x, const float* __restrict__ emb,
               const float* __restrict__ fcb,
               const short* __restrict__ W0, const short* __restrict__ W1,
               const short* __restrict__ FCW,
               const float* __restrict__ b0, const float* __restrict__ b1,
               short* __restrict__ h0b, short* __restrict__ h1b,
               unsigned* __restrict__ flags,
               float* __restrict__ out)
{
  extern __shared__ short lds[];
  short* Wl0  = lds;            // 24576 shorts (48 KB)
  short* Wl1  = lds + 24576;    // 32768 shorts (64 KB)
  short* fcs  = lds + 57344;    // 12288 shorts (24 KB)
  short* embs = lds + 69632;    // 36*136 = 4896 shorts
  float* invlen_l = (float*)(lds + 74528); // 16 floats

  const int tid  = threadIdx.x;
  const int lane = tid & 63;
  const int w    = tid >> 6;      // 0..15
  const int l15  = lane & 15;
  const int l4   = lane >> 4;

  const int b = blockIdx.x;
  const int g = (b & 7) + 8*(b >> 7);
  const int q = (b >> 3) & 15;

  unsigned* grp_flags = flags + g*512;          // 16 lines x 32 uints
  unsigned* my_flag   = grp_flags + q*32;
  short* gh0 = h0b + g*GRP;
  short* gh1 = h1b + g*GRP;

  // ---- prologue: stage LDS (panels pre-zeroed by memsetAsync) ----
  for (int i = tid; i < 24576; i += 1024) Wl0[i] = W0[q*24576 + i];
  for (int i = tid; i < 32768; i += 1024) Wl1[i] = W1[q*32768 + i];
  for (int i = tid; i < 12288; i += 1024) fcs[i] = FCW[i];
  for (int i = tid; i < 36*128; i += 1024) {
    int r = i >> 7, c = i & 127;
    embs[r*136 + c] = f2bf(emb[i]);
  }
  if (tid < 16) {
    int row = g*256 + q*16 + tid;
    int cnt = 0;
    for (int s = 0; s < SLEN; s++) cnt += (x[(size_t)row*SLEN + s] != 0) ? 1 : 0;
    invlen_l[tid] = 1.0f / (float)cnt;
  }
  __syncthreads();
  if (tid == 0) stflag_sc(my_flag, 1u);

  // hoisted invariants
  const int ch = 16*q + l15;
  const float bi0 = b0[ch], bf0 = b0[256+ch], bg0 = b0[512+ch], bo0 = b0[768+ch];
  const float bi1 = b1[ch], bf1 = b1[256+ch], bg1 = b1[512+ch], bo1 = b1[768+ch];
  const bool  v2  = (l15 < 4);
  const float lb0 = fcb[l15], lb1 = fcb[16 + l15];
  const float lb2 = v2 ? fcb[32 + l15] : 0.f;

  float c0s[2][4] = {};
  float c1s[2][4] = {};
  float mloss[4] = {0.f,0.f,0.f,0.f};

  for (int t = 0; t <= 128; t++) {
    // hoist x loads (never depend on panels)
    int tok0 = 0, tok1 = 0, tg4[4] = {0,0,0,0};
    if (w < 8 && t <= 126) {
      tok0 = x[(size_t)(g*256 + 32*w      + l15)*SLEN + t];
      tok1 = x[(size_t)(g*256 + 32*w + 16 + l15)*SLEN + t];
    }
    if (w == 7 && t >= 2) {
      #pragma unroll
      for (int j = 0; j < 4; j++)
        tg4[j] = x[(size_t)(g*256 + 16*q + 4*l4 + j)*SLEN + (t-1)];   // target of step t-2
    }

    // ---- flag rendezvous (fence-free): lane i polls sibling i's line ----
    if (tid < 16) {
      const unsigned* fp = grp_flags + tid*32;
      while (ldflag_sc(fp) < (unsigned)(t+1))
        __builtin_amdgcn_s_sleep(1);
    }
    __syncthreads();

    if (w < 8) {
      // ================= L0: h0(t), rows 32w..32w+32, ch 16q..16q+16 =========
      if (t <= 126) {
        const short* hsrc = gh0 + ((t^1)&1)*SLOT;      // h0(t-1)
        const short* aA = hsrc + (32*w      + l15)*32 + l4*8;
        const short* aB = hsrc + (32*w + 16 + l15)*32 + l4*8;
        f32x4 acc[2][4] = {};
        #pragma unroll
        for (int kt = 0; kt < 4; kt++) {               // emb part (LDS)
          bf16x8 Bf[4];
          #pragma unroll
          for (int G = 0; G < 4; G++)
            Bf[G] = *(const bf16x8*)(Wl0 + (G*12 + kt)*512 + lane*8);
          bf16x8 A0 = *(const bf16x8*)(embs + tok0*136 + kt*32 + l4*8);
          bf16x8 A1 = *(const bf16x8*)(embs + tok1*136 + kt*32 + l4*8);
          #pragma unroll
          for (int G = 0; G < 4; G++) {
            acc[0][G] = __builtin_amdgcn_mfma_f32_16x16x32_bf16(A0, Bf[G], acc[0][G], 0, 0, 0);
            acc[1][G] = __builtin_amdgcn_mfma_f32_16x16x32_bf16(A1, Bf[G], acc[1][G], 0, 0, 0);
          }
        }
        #pragma unroll
        for (int hf = 0; hf < 2; hf++) {               // h part (MALL, batched)
          bf16x8 SA[4], SB[4];
          #pragma unroll
          for (int i = 0; i < 4; i++) {
            ld16_sc(&SA[i], aA + (hf*4 + i)*8192);
            ld16_sc(&SB[i], aB + (hf*4 + i)*8192);
          }
          vmdrain_sb();
          #pragma unroll
          for (int i = 0; i < 4; i++) {
            int kt = 4 + hf*4 + i;
            bf16x8 Bf[4];
            #pragma unroll
            for (int G = 0; G < 4; G++)
              Bf[G] = *(const bf16x8*)(Wl0 + (G*12 + kt)*512 + lane*8);
            #pragma unroll
            for (int G = 0; G < 4; G++) {
              acc[0][G] = __builtin_amdgcn_mfma_f32_16x16x32_bf16(SA[i], Bf[G], acc[0][G], 0, 0, 0);
              acc[1][G] = __builtin_amdgcn_mfma_f32_16x16x32_bf16(SB[i], Bf[G], acc[1][G], 0, 0, 0);
            }
          }
        }
        short* hdst = gh0 + (t&1)*SLOT + (q>>1)*8192 + (q&1)*16 + l15;
        #pragma unroll
        for (int m = 0; m < 2; m++)
          #pragma unroll
          for (int j = 0; j < 4; j++) {
            float iv = fsig (acc[m][0][j] + bi0);
            float fv = fsig (acc[m][1][j] + bf0);
            float gv = ftanh(acc[m][2][j] + bg0);
            float ov = fsig (acc[m][3][j] + bo0);
            float c  = fv * c0s[m][j] + iv * gv;
            c0s[m][j] = c;
            st2_sc(hdst + (32*w + 16*m + 4*l4 + j)*32, f2bf(ov * ftanh(c)));
          }
      }
      // ================= FC + softmax + loss for step t-2 (wave 7) ===========
      if (w == 7 && t >= 2) {
        const short* h1c = gh1 + (t&1)*SLOT;           // h1(t-2)
        const short* fb  = h1c + (16*q + l15)*32 + l4*8;
        f32x4 a3[3] = {};
        #pragma unroll
        for (int hf = 0; hf < 2; hf++) {
          bf16x8 SA[4];
          #pragma unroll
          for (int i = 0; i < 4; i++)
            ld16_sc(&SA[i], fb + (hf*4 + i)*8192);
          vmdrain_sb();
          #pragma unroll
          for (int i = 0; i < 4; i++) {
            int kt = hf*4 + i;
            #pragma unroll
            for (int n = 0; n < 3; n++) {
              bf16x8 Bf = *(const bf16x8*)(fcs + (n*8 + kt)*512 + lane*8);
              a3[n] = __builtin_amdgcn_mfma_f32_16x16x32_bf16(SA[i], Bf, a3[n], 0, 0, 0);
            }
          }
        }
        #pragma unroll
        for (int j = 0; j < 4; j++) {
          float g0 = fmaxf(a3[0][j] + lb0, 0.f);
          float g1 = fmaxf(a3[1][j] + lb1, 0.f);
          float g2 = v2 ? fmaxf(a3[2][j] + lb2, 0.f) : -INFINITY;
          float mx = fmaxf(fmaxf(g0, g1), g2);
          #pragma unroll
          for (int k = 1; k < 16; k <<= 1) mx = fmaxf(mx, __shfl_xor(mx, k, 64));
          float e0 = __expf(g0 - mx), e1 = __expf(g1 - mx);
          float e2 = v2 ? __expf(g2 - mx) : 0.f;
          float sm = e0 + e1 + e2;
          #pragma unroll
          for (int k = 1; k < 16; k <<= 1) sm += __shfl_xor(sm, k, 64);
          float inv = 1.0f / sm;
          int grow = g*256 + 16*q + 4*l4 + j;
          float* po = out + ((size_t)grow*TLEN + (t-2))*VOC;
          __builtin_nontemporal_store(e0 * inv, po + l15);
          __builtin_nontemporal_store(e1 * inv, po + 16 + l15);
          if (v2) __builtin_nontemporal_store(e2 * inv, po + 32 + l15);
          int tg = tg4[j];
          float sel = (tg < 16) ? g0 : ((tg < 32) ? g1 : g2);
          float ltg = __shfl(sel, (lane & 48) | (tg & 15), 64);
          float nll = mx + __logf(sm) - ltg;
          mloss[j] += (tg != 0) ? nll * invlen_l[4*l4 + j] : 0.f;
        }
      }
    } else {
      // ================= L1: h1(t-1), rows 32w8..+32, ch 16q..16q+16 =========
      if (t >= 1 && t <= 127) {
        const int w8 = w - 8;
        const int s  = t - 1;
        const short* h0src = gh0 + (s&1)*SLOT;         // h0(s)
        const short* h1src = gh1 + ((s^1)&1)*SLOT;     // h1(s-1)
        const short* s0A = h0src + (32*w8      + l15)*32 + l4*8;
        const short* s0B = h0src + (32*w8 + 16 + l15)*32 + l4*8;
        const short* s1A = h1src + (32*w8      + l15)*32 + l4*8;
        const short* s1B = h1src + (32*w8 + 16 + l15)*32 + l4*8;
        f32x4 acc[2][4] = {};
        #pragma unroll
        for (int hf = 0; hf < 4; hf++) {
          bf16x8 SA[4], SB[4];
          #pragma unroll
          for (int i = 0; i < 4; i++) {
            int kt = hf*4 + i;
            const short* pA = (kt < 8) ? (s0A + kt*8192) : (s1A + (kt-8)*8192);
            const short* pB = (kt < 8) ? (s0B + kt*8192) : (s1B + (kt-8)*8192);
            ld16_sc(&SA[i], pA);
            ld16_sc(&SB[i], pB);
          }
          vmdrain_sb();
          #pragma unroll
          for (int i = 0; i < 4; i++) {
            int kt = hf*4 + i;
            bf16x8 Bf[4];
            #pragma unroll
            for (int G = 0; G < 4; G++)
              Bf[G] = *(const bf16x8*)(Wl1 + (G*16 + kt)*512 + lane*8);
            #pragma unroll
            for (int G = 0; G < 4; G++) {
              acc[0][G] = __builtin_amdgcn_mfma_f32_16x16x32_bf16(SA[i], Bf[G], acc[0][G], 0, 0, 0);
              acc[1][G] = __builtin_amdgcn_mfma_f32_16x16x32_bf16(SB[i], Bf[G], acc[1][G], 0, 0, 0);
            }
          }
        }
        short* hdst = gh1 + (s&1)*SLOT + (q>>1)*8192 + (q&1)*16 + l15;
        #pragma unroll
        for (int m = 0; m < 2; m++)
          #pragma unroll
          for (int j = 0; j < 4; j++) {
            float iv = fsig (acc[m][0][j] + bi1);
            float fv = fsig (acc[m][1][j] + bf1);
            float gv = ftanh(acc[m][2][j] + bg1);
            float ov = fsig (acc[m][3][j] + bo1);
            float c  = fv * c1s[m][j] + iv * gv;
            c1s[m][j] = c;
            st2_sc(hdst + (32*w8 + 16*m + 4*l4 + j)*32, f2bf(ov * ftanh(c)));
          }
      }
    }

    // drain own sc01 panel stores, then rendezvous-post
    asm volatile("s_waitcnt vmcnt(0)" ::: "memory");
    __syncthreads();
    if (tid == 0 && t < 128)
      stflag_sc(my_flag, (unsigned)(t+2));
  } // tick loop

  if (w == 7 && l15 == 0) {
    float tot = 0.f;
    #pragma unroll
    for (int j = 0; j < 4; j++) {
      int grow = g*256 + 16*q + 4*l4 + j;
      __builtin_nontemporal_store(mloss[j], out + (size_t)MLOSS_OFF + grow);
      tot += mloss[j];
    }
    atomicAdd(out + LOSS_OFF, tot * (1.0f/4096.0f));
  }
}

// ===================== fallback (R2-style, ~9.6 ms) =====================
__global__ __launch_bounds__(1024, 4)
void lstm_small(const int* __restrict__ x, const float* __restrict__ emb,
                const float* __restrict__ fcb,
                const short* __restrict__ W0, const short* __restrict__ W1,
                const short* __restrict__ FCW,
                const float* __restrict__ b0, const float* __restrict__ b1,
                float* __restrict__ out)
{
  __shared__ __align__(16) short emb_s[36*136];
  __shared__ __align__(16) short h0_s[32*264];
  __shared__ __align__(16) short h1_s[32*264];
  __shared__ int   tok_s[32];
  __shared__ float invlen_s[32];

  const int tid  = threadIdx.x;
  const int lane = tid & 63;
  const int wv   = tid >> 6;
  const int l15  = lane & 15;
  const int l4   = lane >> 4;
  const int r0   = blockIdx.x * 32;

  for (int i = tid; i < 36*128; i += 1024) {
    int r = i >> 7, c = i & 127;
    emb_s[r*136 + c] = f2bf(emb[i]);
  }
  for (int i = tid; i < 32*264; i += 1024) { h0_s[i] = 0; h1_s[i] = 0; }
  if (tid < 32) {
    int cnt = 0;
    for (int s = 0; s < SLEN; s++) cnt += (x[(r0+tid)*SLEN + s] != 0) ? 1 : 0;
    invlen_s[tid] = 1.0f / (float)cnt;
    tok_s[tid] = x[(r0+tid)*SLEN + 0];
  }
  __syncthreads();

  const int ch = wv*16 + l15;
  const short* w0base = W0 + wv*24576 + lane*8;
  const short* w1base = W1 + wv*32768 + lane*8;
  const short* fcbase = FCW + lane*8;
  const float bi0 = b0[ch], bf0 = b0[256+ch], bg0 = b0[512+ch], bo0 = b0[768+ch];
  const float bi1 = b1[ch], bf1 = b1[256+ch], bg1 = b1[512+ch], bo1 = b1[768+ch];
  const bool  v2  = (l15 < 4);
  const float lb0 = fcb[l15], lb1 = fcb[16 + l15];
  const float lb2 = v2 ? fcb[32 + l15] : 0.f;

  float c0s[2][4] = {};
  float c1s[2][4] = {};
  float mloss[4] = {0.f,0.f,0.f,0.f};

  for (int t = 0; t < TLEN; t++) {
    int tokv[2];
    #pragma unroll
    for (int m = 0; m < 2; m++) tokv[m] = tok_s[m*16 + l15];
    float hn0[2][4];
    {
      f32x4 acc[2][4] = {};
      #pragma unroll
      for (int kt = 0; kt < 12; kt++) {
        bf16x8 Bf[4];
        #pragma unroll
        for (int G = 0; G < 4; G++) Bf[G] = *(const bf16x8*)(w0base + (G*12 + kt)*512);
        bf16x8 Af[2];
        #pragma unroll
        for (int m = 0; m < 2; m++) {
          if (kt < 4) Af[m] = *(const bf16x8*)(emb_s + tokv[m]*136 + kt*32 + l4*8);
          else        Af[m] = *(const bf16x8*)(h0_s + (m*16 + l15)*264 + (kt-4)*32 + l4*8);
        }
        #pragma unroll
        for (int m = 0; m < 2; m++)
          #pragma unroll
          for (int G = 0; G < 4; G++)
            acc[m][G] = __builtin_amdgcn_mfma_f32_16x16x32_bf16(Af[m], Bf[G], acc[m][G], 0, 0, 0);
      }
      #pragma unroll
      for (int m = 0; m < 2; m++)
        #pragma unroll
        for (int j = 0; j < 4; j++) {
          float iv = fsig (acc[m][0][j] + bi0);
          float fv = fsig (acc[m][1][j] + bf0);
          float gv = ftanh(acc[m][2][j] + bg0);
          float ov = fsig (acc[m][3][j] + bo0);
          float c  = fv * c0s[m][j] + iv * gv;
          c0s[m][j] = c;
          hn0[m][j] = ov * ftanh(c);
        }
    }
    __syncthreads();
    if (wv == 15 && lane < 32) tok_s[lane] = x[(r0+lane)*SLEN + t + 1];
    #pragma unroll
    for (int m = 0; m < 2; m++)
      #pragma unroll
      for (int j = 0; j < 4; j++)
        h0_s[(m*16 + l4*4 + j)*264 + ch] = f2bf(hn0[m][j]);
    __syncthreads();
    float hn1[2][4];
    {
      f32x4 acc[2][4] = {};
      #pragma unroll
      for (int kt = 0; kt < 16; kt++) {
        bf16x8 Bf[4];
        #pragma unroll
        for (int G = 0; G < 4; G++) Bf[G] = *(const bf16x8*)(w1base + (G*16 + kt)*512);
        bf16x8 Af[2];
        #pragma unroll
        for (int m = 0; m < 2; m++) {
          if (kt < 8) Af[m] = *(const bf16x8*)(h0_s + (m*16 + l15)*264 + kt*32 + l4*8);
          else        Af[m] = *(const bf16x8*)(h1_s + (m*16 + l15)*264 + (kt-8)*32 + l4*8);
        }
        #pragma unroll
        for (int m = 0; m < 2; m++)
          #pragma unroll
          for (int G = 0; G < 4; G++)
            acc[m][G] = __builtin_amdgcn_mfma_f32_16x16x32_bf16(Af[m], Bf[G], acc[m][G], 0, 0, 0);
      }
      #pragma unroll
      for (int m = 0; m < 2; m++)
        #pragma unroll
        for (int j = 0; j < 4; j++) {
          float iv = fsig (acc[m][0][j] + bi1);
          float fv = fsig (acc[m][1][j] + bf1);
          float gv = ftanh(acc[m][2][j] + bg1);
          float ov = fsig (acc[m][3][j] + bo1);
          float c  = fv * c1s[m][j] + iv * gv;
          c1s[m][j] = c;
          hn1[m][j] = ov * ftanh(c);
        }
    }
    __syncthreads();
    #pragma unroll
    for (int m = 0; m < 2; m++)
      #pragma unroll
      for (int j = 0; j < 4; j++)
        h1_s[(m*16 + l4*4 + j)*264 + ch] = f2bf(hn1[m][j]);
    __syncthreads();
    if (wv < 2) {
      const int wr = wv * 16;
      f32x4 a3[3] = {};
      #pragma unroll
      for (int kt = 0; kt < 8; kt++) {
        bf16x8 Ah = *(const bf16x8*)(h1_s + (wr + l15)*264 + kt*32 + l4*8);
        #pragma unroll
        for (int n = 0; n < 3; n++) {
          bf16x8 Bf = *(const bf16x8*)(fcbase + (n*8 + kt)*512);
          a3[n] = __builtin_amdgcn_mfma_f32_16x16x32_bf16(Ah, Bf, a3[n], 0, 0, 0);
        }
      }
      #pragma unroll
      for (int j = 0; j < 4; j++) {
        float g0 = fmaxf(a3[0][j] + lb0, 0.f);
        float g1 = fmaxf(a3[1][j] + lb1, 0.f);
        float g2 = v2 ? fmaxf(a3[2][j] + lb2, 0.f) : -INFINITY;
        float mx = fmaxf(fmaxf(g0, g1), g2);
        #pragma unroll
        for (int k = 1; k < 16; k <<= 1) mx = fmaxf(mx, __shfl_xor(mx, k, 64));
        float e0 = __expf(g0 - mx), e1 = __expf(g1 - mx);
        float e2 = v2 ? __expf(g2 - mx) : 0.f;
        float sm = e0 + e1 + e2;
        #pragma unroll
        for (int k = 1; k < 16; k <<= 1) sm += __shfl_xor(sm, k, 64);
        float inv = 1.0f / sm;
        int row = wr + l4*4 + j;
        float* po = out + ((size_t)(r0 + row)*TLEN + t)*VOC;
        __builtin_nontemporal_store(e0 * inv, po + l15);
        __builtin_nontemporal_store(e1 * inv, po + 16 + l15);
        if (v2) __builtin_nontemporal_store(e2 * inv, po + 32 + l15);
        int tg = tok_s[row];
        float sel = (tg < 16) ? g0 : ((tg < 32) ? g1 : g2);
        float ltg = __shfl(sel, (lane & 48) | (tg & 15), 64);
        float nll = mx + __logf(sm) - ltg;
        mloss[j] += (tg != 0) ? nll * invlen_s[row] : 0.f;
      }
    }
  }
  if (wv < 2 && l15 == 0) {
    float tot = 0.f;
    #pragma unroll
    for (int j = 0; j < 4; j++) {
      int row = wv*16 + l4*4 + j;
      __builtin_nontemporal_store(mloss[j], out + (size_t)MLOSS_OFF + r0 + row);
      tot += mloss[j];
    }
    atomicAdd(out + LOSS_OFF, tot * (1.0f/4096.0f));
  }
}

extern "C" void kernel_launch(void* const* d_in, const int* in_sizes, int n_in,
                              void* d_out, int out_size, void* d_ws, size_t ws_size,
                              hipStream_t stream) {
  const int*   x    = (const int*)  d_in[0];
  const float* emb  = (const float*)d_in[1];
  const float* Wih0 = (const float*)d_in[2];
  const float* Whh0 = (const float*)d_in[3];
  const float* bih0 = (const float*)d_in[4];
  const float* bhh0 = (const float*)d_in[5];
  const float* Wih1 = (const float*)d_in[6];
  const float* Whh1 = (const float*)d_in[7];
  const float* bih1 = (const float*)d_in[8];
  const float* bhh1 = (const float*)d_in[9];
  const float* fcW  = (const float*)d_in[10];
  const float* fcb  = (const float*)d_in[11];

  short* w0  = (short*)((char*)d_ws + WS_W0);
  short* w1  = (short*)((char*)d_ws + WS_W1);
  short* fcw = (short*)((char*)d_ws + WS_FC);
  float* b0  = (float*)((char*)d_ws + WS_B0);
  float* b1  = (float*)((char*)d_ws + WS_B1);
  float* out = (float*)d_out;

  bool big = (ws_size >= (size_t)WS_NEEDED);
  static int lds_ok = -1;
  if (big && lds_ok < 0) {
    hipError_t e = hipFuncSetAttribute((const void*)lstm_fuse,
                     hipFuncAttributeMaxDynamicSharedMemorySize, 149504);
    lds_ok = (e == hipSuccess) ? 1 : 0;
  }
  bool use_pipe = big && (lds_ok == 1);

  short*    h0bp = (short*)((char*)d_ws + WS_H0);
  short*    h1bp = (short*)((char*)d_ws + WS_H1);
  unsigned* ctr  = (unsigned*)((char*)d_ws + WS_CTR);

  prep_kernel<<<3640, 256, 0, stream>>>(Wih0, Whh0, bih0, bhh0, Wih1, Whh1,
                                        bih1, bhh1, fcW, w0, w1, fcw, b0, b1, out);
  if (use_pipe) {
    // zero panels + flags (kernel-boundary coherence; re-done every launch)
    hipMemsetAsync((char*)d_ws + WS_H0, 0, (size_t)(WS_NEEDED - WS_H0), stream);
    lstm_fuse<<<256, 1024, 149504, stream>>>(x, emb, fcb, w0, w1, fcw, b0, b1,
                                             h0bp, h1bp, ctr, out);
  } else {
    lstm_small<<<128, 1024, 0, stream>>>(x, emb, fcb, w0, w1, fcw, b0, b1, out);
  }
}